// Round 9
// baseline (805.929 us; speedup 1.0000x reference)
//
#include <hip/hip_runtime.h>
#include <stdint.h>

#define TT 4
#define BB 8
#define NN 2048
#define KNB 16
#define PP (NN*KNB)
#define VTH 1.0f
#define EPSB 1e-5f

typedef unsigned long long u64;
typedef unsigned int u32;
typedef unsigned short u16;
typedef unsigned char u8;
typedef __attribute__((ext_vector_type(8))) short short8;
typedef __attribute__((ext_vector_type(4))) float f4;

#define GLOAD_LDS16(g, l) __builtin_amdgcn_global_load_lds( \
    (const __attribute__((address_space(1))) u32*)(g), \
    (__attribute__((address_space(3))) u32*)(l), 16, 0, 0)

__device__ __forceinline__ float lif_step(float& v, float x) {
    v = v + (x - v) / 2.0f;
    float s = (v - VTH >= 0.0f) ? 1.0f : 0.0f;
    v = v * (1.0f - s);
    return s;
}

// ---------------- T-Net ----------------
__global__ __launch_bounds__(256) void k_tnet1(const float* __restrict__ x, const float* __restrict__ w,
        const float* __restrict__ bi, u64* __restrict__ s1b) {
    int i = blockIdx.x*256 + threadIdx.x;
    int b = i >> 11, n = i & 2047;
    float p0 = x[((size_t)b*14+0)*NN+n];
    float p1 = x[((size_t)b*14+1)*NN+n];
    float p2 = x[((size_t)b*14+2)*NN+n];
    u64 m[TT] = {0,0,0,0};
    for (int d = 0; d < 64; ++d) {
        float z = ((w[d*3+0]*p0 + w[d*3+1]*p1) + w[d*3+2]*p2) + bi[d];
        float v = 0.f;
        #pragma unroll
        for (int t = 0; t < TT; ++t) {
            float s = lif_step(v, z);
            if (s != 0.f) m[t] |= (1ull << d);
        }
    }
    #pragma unroll
    for (int t = 0; t < TT; ++t) s1b[((size_t)t*BB + b)*NN + n] = m[t];
}

// conv2: 64->128, split over 4 channel-chunks of 32 for occupancy
__global__ __launch_bounds__(256) void k_tnet2(const u64* __restrict__ s1b, const float* __restrict__ w,
        const float* __restrict__ bi, u32* __restrict__ s2b32) {
    __shared__ float ws[32*64];
    int tid = threadIdx.x;
    int ec = blockIdx.y;
    for (int l = tid; l < 32*64; l += 256) ws[l] = w[ec*32*64 + l];
    __syncthreads();
    int i = blockIdx.x*256 + tid;
    int b = i >> 11, n = i & 2047;
    u64 m[TT];
    #pragma unroll
    for (int t = 0; t < TT; ++t) m[t] = s1b[((size_t)t*BB+b)*NN+n];
    u32 o[TT] = {0,0,0,0};
    for (int el = 0; el < 32; ++el) {
        float z[TT] = {0.f,0.f,0.f,0.f};
        #pragma unroll 8
        for (int d = 0; d < 64; ++d) {
            float wv = ws[el*64+d];
            #pragma unroll
            for (int t = 0; t < TT; ++t) z[t] += ((m[t]>>d)&1ull) ? wv : 0.f;
        }
        float v = 0.f, bb = bi[ec*32 + el];
        #pragma unroll
        for (int t = 0; t < TT; ++t) {
            float s = lif_step(v, z[t] + bb);
            if (s != 0.f) o[t] |= (1u << el);
        }
    }
    #pragma unroll
    for (int t = 0; t < TT; ++t)
        s2b32[(((size_t)t*BB+b)*NN+n)*4 + ec] = o[t];
}

// FC head, wave-parallel
__global__ __launch_bounds__(64) void k_fc1(const u32* __restrict__ mx, const float* __restrict__ fw1,
        const float* __restrict__ fb1, float* __restrict__ h1v) {
    int f = blockIdx.x, b = blockIdx.y, lane = threadIdx.x;
    float wr[16];
    #pragma unroll
    for (int j = 0; j < 16; ++j) wr[j] = fw1[(size_t)f*1024 + j*64 + lane];
    float z[TT];
    #pragma unroll
    for (int t = 0; t < TT; ++t) {
        float s = 0.f;
        #pragma unroll
        for (int j = 0; j < 16; ++j)
            s += wr[j] * (float)mx[((size_t)t*BB+b)*1024 + j*64 + lane];
        #pragma unroll
        for (int o = 1; o < 64; o <<= 1) s += __shfl_xor(s, o, 64);
        z[t] = s;
    }
    if (lane == 0) {
        float v = 0.f;
        #pragma unroll
        for (int t = 0; t < TT; ++t)
            h1v[((size_t)t*BB+b)*512 + f] = lif_step(v, z[t] + fb1[f]);
    }
}

__global__ __launch_bounds__(64) void k_fc2(const float* __restrict__ h1v, const float* __restrict__ fw2,
        const float* __restrict__ fb2, float* __restrict__ h2v) {
    int f = blockIdx.x, b = blockIdx.y, lane = threadIdx.x;
    float wr[8];
    #pragma unroll
    for (int j = 0; j < 8; ++j) wr[j] = fw2[(size_t)f*512 + j*64 + lane];
    float z[TT];
    #pragma unroll
    for (int t = 0; t < TT; ++t) {
        float s = 0.f;
        #pragma unroll
        for (int j = 0; j < 8; ++j)
            s += wr[j] * h1v[((size_t)t*BB+b)*512 + j*64 + lane];
        #pragma unroll
        for (int o = 1; o < 64; o <<= 1) s += __shfl_xor(s, o, 64);
        z[t] = s;
    }
    if (lane == 0) {
        float v = 0.f;
        #pragma unroll
        for (int t = 0; t < TT; ++t)
            h2v[((size_t)t*BB+b)*256 + f] = lif_step(v, z[t] + fb2[f]);
    }
}

__global__ __launch_bounds__(64) void k_fc3(const float* __restrict__ h2v, const float* __restrict__ fw3,
        const float* __restrict__ fb3, float* __restrict__ trans) {
    __shared__ float h3s[TT][9];
    int b = blockIdx.x, tid = threadIdx.x;
    if (tid < TT*9) {
        int t = tid/9, oo = tid%9;
        float z = 0.f;
        for (int c = 0; c < 256; ++c) z += fw3[oo*256+c]*h2v[((size_t)t*BB+b)*256 + c];
        h3s[t][oo] = z + fb3[oo];
    }
    __syncthreads();
    if (tid < 9) {
        float m = ((h3s[0][tid]+h3s[1][tid]) + (h3s[2][tid]+h3s[3][tid])) * 0.25f;
        int c = tid/3, dd = tid%3;
        trans[b*9+tid] = m + ((c==dd)?1.0f:0.0f);
    }
}

// apply transform; also emit packed float4 (x,y,z,sq) for KNN
__global__ __launch_bounds__(256) void k_trans(const float* __restrict__ x, const float* __restrict__ tr,
        float* __restrict__ xa, float4* __restrict__ xa4) {
    int i = blockIdx.x*256 + threadIdx.x;
    int b = i >> 11, n = i & 2047;
    float p0 = x[((size_t)b*14+0)*NN+n];
    float p1 = x[((size_t)b*14+1)*NN+n];
    float p2 = x[((size_t)b*14+2)*NN+n];
    const float* tb = tr + b*9;
    float a0 = (p0*tb[0] + p1*tb[3]) + p2*tb[6];
    float a1 = (p0*tb[1] + p1*tb[4]) + p2*tb[7];
    float a2 = (p0*tb[2] + p1*tb[5]) + p2*tb[8];
    xa[((size_t)b*14+0)*NN+n] = a0;
    xa[((size_t)b*14+1)*NN+n] = a1;
    xa[((size_t)b*14+2)*NN+n] = a2;
    for (int c = 3; c < 14; ++c) xa[((size_t)b*14+c)*NN+n] = x[((size_t)b*14+c)*NN+n];
    float4 p;
    p.x = a0; p.y = a1; p.z = a2;
    p.w = (a0*a0 + a1*a1) + a2*a2;
    xa4[(size_t)b*NN+n] = p;
}

// KNN: one wave per query point
__global__ __launch_bounds__(256) void k_knn(const float4* __restrict__ xa4, int* __restrict__ idx) {
    int wave = threadIdx.x >> 6, lane = threadIdx.x & 63;
    int b = blockIdx.y;
    int n = blockIdx.x*4 + wave;
    const float4* P = xa4 + (size_t)b*NN;
    float4 q = P[n];
    float sn = q.w;
    float vals[32];
    #pragma unroll
    for (int j = 0; j < 32; ++j) {
        float4 p = P[j*64 + lane];
        float inner = (q.x*p.x + q.y*p.y) + q.z*p.z;
        vals[j] = (2.0f*inner - sn) - p.w;
    }
    for (int k = 0; k < KNB; ++k) {
        float bv = -3.4e38f; int bj = 0;
        #pragma unroll
        for (int j = 0; j < 32; ++j) if (vals[j] > bv) { bv = vals[j]; bj = j; }
        int bm = bj*64 + lane;
        u32 fb = __float_as_uint(bv);
        fb = (fb & 0x80000000u) ? ~fb : (fb | 0x80000000u);
        u64 key = ((u64)fb << 32) | (u32)(~bm);
        #pragma unroll
        for (int o2 = 1; o2 < 64; o2 <<= 1) {
            u64 other = __shfl_xor(key, o2, 64);
            key = (other > key) ? other : key;
        }
        int wm = (int)(~(u32)key);
        if (lane == 0) idx[((size_t)b*NN + n)*KNB + k] = wm;
        int wl = wm & 63, wj = wm >> 6;
        if (lane == wl) {
            #pragma unroll
            for (int j = 0; j < 32; ++j) if (j == wj) vals[j] = -3.4e38f;
        }
    }
}

// fused graph-feature + edge conv1 GEMM: z once + stats partials (bit-identical z)
__global__ __launch_bounds__(256) void k_zstats(const float* __restrict__ xa, const int* __restrict__ idx,
        const float* __restrict__ w1, float* __restrict__ part1, float* __restrict__ z1) {
    __shared__ float w1s[64*28];
    __shared__ float wsum[4][64], wsq[4][64];
    int pt = blockIdx.x, b = blockIdx.y;
    int p0 = pt*256, tid = threadIdx.x;
    int p = p0 + tid;
    for (int l = tid; l < 64*28; l += 256) w1s[l] = w1[l];
    __syncthreads();
    int n = p >> 4;
    int mm = idx[((size_t)b*NN+n)*KNB + (p & 15)];
    float gr[28];
    #pragma unroll
    for (int c = 0; c < 14; ++c) {
        float ctr = xa[((size_t)b*14+c)*NN + n];
        float nb  = xa[((size_t)b*14+c)*NN + mm];
        gr[c] = ctr;
        gr[14+c] = nb - ctr;
    }
    int wv = tid>>6, lane = tid&63;
    for (int d = 0; d < 64; ++d) {
        float z = 0.f;
        #pragma unroll
        for (int c = 0; c < 28; ++c) z += w1s[d*28+c]*gr[c];
        z1[((size_t)b*64+d)*PP + p] = z;
        float s = z, q = z*z;
        #pragma unroll
        for (int o = 1; o < 64; o <<= 1) { s += __shfl_xor(s, o, 64); q += __shfl_xor(q, o, 64); }
        if (lane == 0) { wsum[wv][d] = s; wsq[wv][d] = q; }
    }
    __syncthreads();
    if (tid < 64) {
        float s = (wsum[0][tid]+wsum[1][tid])+(wsum[2][tid]+wsum[3][tid]);
        float q = (wsq[0][tid]+wsq[1][tid])+(wsq[2][tid]+wsq[3][tid]);
        size_t blk = (size_t)b*128 + pt;
        part1[(blk*64 + tid)*2+0] = s;
        part1[(blk*64 + tid)*2+1] = q;
    }
}

__global__ __launch_bounds__(256) void k_reduce(const float* __restrict__ part, float* __restrict__ stats, int nch, int nblk, double M) {
    __shared__ double sred[256], qred[256];
    int ch = blockIdx.x, tid = threadIdx.x;
    double s = 0.0, q = 0.0;
    for (int i = tid; i < nblk; i += 256) {
        s += (double)part[((size_t)i*nch + ch)*2 + 0];
        q += (double)part[((size_t)i*nch + ch)*2 + 1];
    }
    sred[tid] = s; qred[tid] = q;
    __syncthreads();
    for (int off = 128; off > 0; off >>= 1) {
        if (tid < off) { sred[tid] += sred[tid+off]; qred[tid] += qred[tid+off]; }
        __syncthreads();
    }
    if (tid == 0) {
        double mu = sred[0] / M;
        double var = qred[0] / M - mu*mu;
        if (var < 0.0) var = 0.0;
        stats[ch*2+0] = (float)mu;
        stats[ch*2+1] = 1.0f / sqrtf((float)var + EPSB);
    }
}

// edge conv1 apply from stored z1
__global__ __launch_bounds__(256) void k_h1(const float* __restrict__ z1,
        const float* __restrict__ st1, const float* __restrict__ g1, const float* __restrict__ be1,
        u64* __restrict__ h1b, u64* __restrict__ h1n) {
    int tid = threadIdx.x;
    int b = blockIdx.y;
    int p0 = blockIdx.x*256;
    int p = p0 + tid;
    int wordbase = (p0>>6) + (tid>>6);
    u64 pm[TT] = {0,0,0,0};
    for (int d = 0; d < 64; ++d) {
        float z = z1[((size_t)b*64+d)*PP + p];
        float mu = st1[d*2+0], iv = st1[d*2+1];
        float v = 0.f;
        #pragma unroll
        for (int t = 0; t < TT; ++t) {
            float y = (z - mu) * iv * g1[t*64+d] + be1[t*64+d];
            float s = lif_step(v, y);
            u64 m = __ballot(s != 0.f);
            if ((tid & 63) == 0) h1b[((size_t)(t*BB+b)*64 + d)*512 + wordbase] = m;
            pm[t] |= ((u64)(s != 0.f)) << d;
        }
    }
    #pragma unroll
    for (int t = 0; t < TT; ++t) h1n[(size_t)(t*BB+b)*PP + p] = pm[t];
}

// ---------------- Tiled popcount Grams (exact int counts) ----------------
__global__ __launch_bounds__(256) void k_gram_h1(const u64* __restrict__ h1b, int* __restrict__ Mi) {
    __shared__ u64 tw[64*65];
    int tid = threadIdx.x;
    int w0 = blockIdx.x*64;
    int tb = blockIdx.y;
    int t = tb >> 3;
    const u64* src = h1b + (size_t)tb*64*512;
    for (int l = tid; l < 64*64; l += 256) {
        int c = l >> 6, w = l & 63;
        tw[c*65+w] = src[(size_t)c*512 + w0 + w];
    }
    __syncthreads();
    int q = tid >> 4, r = tid & 15;
    int acc[4][4];
    #pragma unroll
    for (int i=0;i<4;++i)
        #pragma unroll
        for (int j=0;j<4;++j) acc[i][j]=0;
    #pragma unroll 4
    for (int w = 0; w < 64; ++w) {
        u64 av[4], bv[4];
        #pragma unroll
        for (int i=0;i<4;++i) av[i] = tw[(q+16*i)*65+w];
        #pragma unroll
        for (int j=0;j<4;++j) bv[j] = tw[(r+16*j)*65+w];
        #pragma unroll
        for (int i=0;i<4;++i)
            #pragma unroll
            for (int j=0;j<4;++j) acc[i][j] += (int)__popcll(av[i]&bv[j]);
    }
    #pragma unroll
    for (int i=0;i<4;++i)
        #pragma unroll
        for (int j=0;j<4;++j)
            atomicAdd(&Mi[((size_t)t*64 + q+16*i)*64 + r+16*j], acc[i][j]);
}

template<int C>
__global__ __launch_bounds__(256) void k_gram2(const u64* __restrict__ bits, int* __restrict__ Mi) {
    __shared__ u64 ta[64*33], tbt[64*33];
    int tid = threadIdx.x;
    int ci0 = blockIdx.x*64, cj0 = blockIdx.y*64;
    int tb = blockIdx.z;
    int t = tb >> 3;
    const u64* srcA = bits + ((size_t)tb*C + ci0)*32;
    const u64* srcB = bits + ((size_t)tb*C + cj0)*32;
    for (int l = tid; l < 64*32; l += 256) {
        int rr = l >> 5, w = l & 31;
        ta[rr*33+w]  = srcA[(size_t)rr*32+w];
        tbt[rr*33+w] = srcB[(size_t)rr*32+w];
    }
    __syncthreads();
    int q = tid >> 4, r = tid & 15;
    int acc[4][4];
    #pragma unroll
    for (int i=0;i<4;++i)
        #pragma unroll
        for (int j=0;j<4;++j) acc[i][j]=0;
    #pragma unroll 4
    for (int w = 0; w < 32; ++w) {
        u64 av[4], bv[4];
        #pragma unroll
        for (int i=0;i<4;++i) av[i] = ta[(q+16*i)*33+w];
        #pragma unroll
        for (int j=0;j<4;++j) bv[j] = tbt[(r+16*j)*33+w];
        #pragma unroll
        for (int i=0;i<4;++i)
            #pragma unroll
            for (int j=0;j<4;++j) acc[i][j] += (int)__popcll(av[i]&bv[j]);
    }
    #pragma unroll
    for (int i=0;i<4;++i)
        #pragma unroll
        for (int j=0;j<4;++j)
            atomicAdd(&Mi[((size_t)t*C + ci0+q+16*i)*C + cj0+r+16*j], acc[i][j]);
}

// project int Gram through weights -> per-(t,ch) (mean, inv_std)
template<int CIN>
__global__ void k_proj(const int* __restrict__ Mf, const float* __restrict__ w,
        float* __restrict__ st, int COUT, double cnt) {
    __shared__ double z2s[256], mns[256];
    int ch = blockIdx.x, t = blockIdx.y, c2 = threadIdx.x;
    const int* Mt = Mf + (size_t)t*CIN*CIN;
    double y = 0.0;
    for (int c = 0; c < CIN; ++c)
        y += (double)w[(size_t)ch*CIN+c] * (double)Mt[(size_t)c*CIN + c2];
    double wc2 = (double)w[(size_t)ch*CIN+c2];
    z2s[c2] = wc2 * y;
    mns[c2] = wc2 * (double)Mt[(size_t)c2*CIN + c2];
    __syncthreads();
    for (int off = CIN>>1; off > 0; off >>= 1) {
        if (c2 < off) { z2s[c2] += z2s[c2+off]; mns[c2] += mns[c2+off]; }
        __syncthreads();
    }
    if (c2 == 0) {
        double mu = mns[0] / cnt;
        double var = z2s[0] / cnt - mu*mu;
        if (var < 0.0) var = 0.0;
        st[((size_t)t*COUT+ch)*2+0] = (float)mu;
        st[((size_t)t*COUT+ch)*2+1] = 1.0f / sqrtf((float)var + EPSB);
    }
}

// weight prep: fp32 w[F][K] -> exact 3-way bf16 split in MFMA-frag layout [K/8][F][8]
__global__ __launch_bounds__(256) void k_wprep(const float* __restrict__ w,
        short* __restrict__ hi, short* __restrict__ mid, short* __restrict__ lo, int F, int K) {
    int i = blockIdx.x*256 + threadIdx.x;
    if (i >= F*K) return;
    int f = i / K, k = i % K;
    float wv = w[i];
    u32 b0 = __float_as_uint(wv);
    float h = __uint_as_float(b0 & 0xFFFF0000u);
    float r1 = wv - h;
    u32 b1 = __float_as_uint(r1);
    float m = __uint_as_float(b1 & 0xFFFF0000u);
    float r2 = r1 - m;
    u32 b2 = __float_as_uint(r2);
    size_t o = ((size_t)(k>>3)*F + f)*8 + (k&7);
    hi[o]  = (short)(b0 >> 16);
    mid[o] = (short)(b1 >> 16);
    lo[o]  = (short)(b2 >> 16);
}

// ---------------- MFMA spike conv: 32 rows/wave (2 A-tiles), KT=64 LDS weight tiles, LUT ----------------
// Wave owns rows [blockIdx.x*128 + wave*32, +32), f-cols [blockIdx.y*64, +64).
// 12 LDS w-frag reads feed 96 MFMAs per 32-k step (2x ratio vs 16-row version).
template<int K, int F, int MODE, bool BITS>
__global__ __launch_bounds__(256) void k_mconv(
        const void* __restrict__ Asrc,
        const short* __restrict__ Whi, const short* __restrict__ Wmd, const short* __restrict__ Wlo,
        const float* __restrict__ st, const float* __restrict__ ga, const float* __restrict__ be,
        const float* __restrict__ bias,
        u16* __restrict__ outp, u32* __restrict__ outm, int NPTS) {
    constexpr int KT = 64;
    constexpr int ROWS = (KT/8)*3;
    constexpr int NW = (K+63)/64;
    __shared__ short wsm[ROWS*512];
    __shared__ short sptab[BITS ? 256*8 : 8];
    __shared__ u32 morr[TT][64];
    int tid = threadIdx.x;
    int wave = tid >> 6, lane = tid & 63;
    int l15 = lane & 15, lg = lane >> 4;
    int b = blockIdx.z;
    int n_base = blockIdx.x*128 + wave*32;
    int f0 = blockIdx.y*64;
    if (MODE == 0 || MODE == 2)
        for (int l = tid; l < TT*64; l += 256) morr[l>>6][l&63] = 0u;
    if (BITS) {
        #pragma unroll
        for (int j = 0; j < 8; ++j) sptab[tid*8+j] = (short)(((tid>>j)&1) * 0x3F80);
    }

    f4 acc[2][4][TT];
    #pragma unroll
    for (int rr = 0; rr < 2; ++rr)
        #pragma unroll
        for (int i = 0; i < 4; ++i)
            #pragma unroll
            for (int t = 0; t < TT; ++t) acc[rr][i][t] = (f4)0.f;

    u64 aw[2][TT][NW];
    const u16* Au[2][TT];
    #pragma unroll
    for (int rr = 0; rr < 2; ++rr)
        #pragma unroll
        for (int t = 0; t < TT; ++t) {
            if (BITS) {
                const u64* Ab = (const u64*)Asrc + ((size_t)(t*BB+b)*NPTS + n_base + rr*16 + l15)*NW;
                #pragma unroll
                for (int wq = 0; wq < NW; ++wq) aw[rr][t][wq] = Ab[wq];
            } else {
                Au[rr][t] = (const u16*)Asrc + ((size_t)(t*BB+b)*NPTS + n_base + rr*16 + l15)*K + lg*8;
            }
        }
    const short* Wsrc[3] = {Whi, Wmd, Wlo};

    #pragma unroll
    for (int kt = 0; kt < K; kt += KT) {
        if (kt > 0) __syncthreads();
        #pragma unroll
        for (int r = wave; r < ROWS; r += 4) {
            int kq = r/3, s = r - kq*3;
            const short* g = Wsrc[s] + ((size_t)((kt>>3) + kq)*F + f0)*8 + lane*8;
            GLOAD_LDS16(g, &wsm[r*512]);
        }
        __syncthreads();
        #pragma unroll
        for (int k0 = 0; k0 < KT; k0 += 32) {
            int kg = kt + k0;
            short8 a[2][TT];
            #pragma unroll
            for (int rr = 0; rr < 2; ++rr)
                #pragma unroll
                for (int t = 0; t < TT; ++t) {
                    if (BITS) {
                        u32 byte = (u32)(aw[rr][t][kg>>6] >> ((kg&63) + lg*8)) & 0xFFu;
                        a[rr][t] = *(const short8*)(sptab + byte*8);
                    } else {
                        a[rr][t] = *(const short8*)(Au[rr][t] + kg);
                    }
                }
            int kql = (k0>>3) + lg;
            #pragma unroll
            for (int fs = 0; fs < 4; ++fs) {
                const short* base = wsm + kql*1536 + (fs*16+l15)*8;
                short8 whi = *(const short8*)(base);
                short8 wmd = *(const short8*)(base + 512);
                short8 wlo = *(const short8*)(base + 1024);
                #pragma unroll
                for (int rr = 0; rr < 2; ++rr)
                    #pragma unroll
                    for (int t = 0; t < TT; ++t) {
                        acc[rr][fs][t] = __builtin_amdgcn_mfma_f32_16x16x32_bf16(a[rr][t], whi, acc[rr][fs][t], 0, 0, 0);
                        acc[rr][fs][t] = __builtin_amdgcn_mfma_f32_16x16x32_bf16(a[rr][t], wmd, acc[rr][fs][t], 0, 0, 0);
                        acc[rr][fs][t] = __builtin_amdgcn_mfma_f32_16x16x32_bf16(a[rr][t], wlo, acc[rr][fs][t], 0, 0, 0);
                    }
            }
        }
    }
    // epilogue: D row = n_base + rr*16 + lg*4 + reg, col f = f0 + fs*16 + l15
    if (MODE == 1) {
        #pragma unroll
        for (int rr = 0; rr < 2; ++rr)
            #pragma unroll
            for (int fs = 0; fs < 4; ++fs) {
                int f = f0 + fs*16 + l15;
                #pragma unroll
                for (int reg = 0; reg < 4; ++reg) {
                    int n = n_base + rr*16 + lg*4 + reg;
                    float v = 0.f;
                    #pragma unroll
                    for (int t = 0; t < TT; ++t) {
                        int ch = t*F + f;
                        float y = (acc[rr][fs][t][reg] - st[(size_t)ch*2+0])*st[(size_t)ch*2+1]*ga[ch] + be[ch];
                        float s = lif_step(v, y);
                        outp[((size_t)(t*BB+b)*NPTS + n)*F + f] = (s != 0.f) ? (u16)0x3F80 : (u16)0;
                    }
                }
            }
    } else if (MODE == 3) {
        #pragma unroll
        for (int rr = 0; rr < 2; ++rr)
            #pragma unroll
            for (int fs = 0; fs < 4; ++fs) {
                int f = f0 + fs*16 + l15;
                u32 nib = 0u;
                #pragma unroll
                for (int reg = 0; reg < 4; ++reg) {
                    float v = 0.f;
                    #pragma unroll
                    for (int t = 0; t < TT; ++t) {
                        int ch = t*F + f;
                        float y = (acc[rr][fs][t][reg] - st[(size_t)ch*2+0])*st[(size_t)ch*2+1]*ga[ch] + be[ch];
                        float s = lif_step(v, y);
                        if (s != 0.f) nib |= (1u << t);
                    }
                }
                nib |= __shfl_xor(nib, 16, 64);
                nib |= __shfl_xor(nib, 32, 64);
                if (lg == 0) {
                    int n_pt = (n_base >> 4) + rr;
                    #pragma unroll
                    for (int t = 0; t < TT; ++t)
                        outp[((size_t)(t*BB+b)*(NPTS>>4) + n_pt)*F + f] = ((nib>>t)&1u) ? (u16)0x3F80 : (u16)0;
                }
            }
    } else {
        #pragma unroll
        for (int fs = 0; fs < 4; ++fs) {
            int f = f0 + fs*16 + l15;
            u32 any[TT] = {0,0,0,0};
            float bb = (MODE == 0) ? bias[f] : 0.f;
            #pragma unroll
            for (int rr = 0; rr < 2; ++rr)
                #pragma unroll
                for (int reg = 0; reg < 4; ++reg) {
                    float v = 0.f;
                    #pragma unroll
                    for (int t = 0; t < TT; ++t) {
                        float y;
                        if (MODE == 0) y = acc[rr][fs][t][reg] + bb;
                        else {
                            int ch = t*F + f;
                            y = (acc[rr][fs][t][reg] - st[(size_t)ch*2+0])*st[(size_t)ch*2+1]*ga[ch] + be[ch];
                        }
                        float s = lif_step(v, y);
                        if (s != 0.f) any[t] = 1u;
                    }
                }
            #pragma unroll
            for (int t = 0; t < TT; ++t) if (any[t]) atomicOr(&morr[t][fs*16+l15], 1u);
        }
        __syncthreads();
        for (int l = tid; l < TT*64; l += 256)
            if (morr[l>>6][l&63]) atomicOr(&outm[((size_t)((l>>6)*BB+b))*F + f0 + (l&63)], 1u);
    }
}

// repack point-major bf16-u16 spikes [t][b][n][C] -> channel-major bits [t][b][C][32 words over n]
template<int C>
__global__ __launch_bounds__(256) void k_repack(const u16* __restrict__ sp, u64* __restrict__ bits) {
    __shared__ u16 tile[64][C+2];
    int tid = threadIdx.x;
    int nw = blockIdx.x, b = blockIdx.y, t = blockIdx.z;
    const u16* src = sp + ((size_t)(t*BB+b)*NN + nw*64)*C;
    for (int i = tid*2; i < 64*C; i += 512) {
        u32 v = *(const u32*)(src + i);
        int r = i / C, c = i % C;
        *(u32*)&tile[r][c] = v;
    }
    __syncthreads();
    int wave = tid >> 6, lane = tid & 63;
    for (int c = wave; c < C; c += 4) {
        u64 m = __ballot(tile[lane][c] != 0);
        if (lane == 0) bits[((size_t)(t*BB+b)*C + c)*32 + nw] = m;
    }
}

__global__ __launch_bounds__(256) void k_out(const u32* __restrict__ mx4, float* __restrict__ out) {
    int i = blockIdx.x*256 + threadIdx.x;
    int b = i >> 10, g = i & 1023;
    float s = (float)(mx4[((size_t)0*BB+b)*1024+g] + mx4[((size_t)1*BB+b)*1024+g]
                    + mx4[((size_t)2*BB+b)*1024+g] + mx4[((size_t)3*BB+b)*1024+g]);
    out[i] = s * 0.25f;
}

extern "C" void kernel_launch(void* const* d_in, const int* in_sizes, int n_in,
                              void* d_out, int out_size, void* d_ws, size_t ws_size,
                              hipStream_t stream) {
    (void)in_sizes; (void)n_in; (void)out_size;
    const float* x    = (const float*)d_in[0];
    const float* tw1  = (const float*)d_in[1];
    const float* tb1  = (const float*)d_in[2];
    const float* tw2  = (const float*)d_in[3];
    const float* tb2  = (const float*)d_in[4];
    const float* tw3  = (const float*)d_in[5];
    const float* tb3  = (const float*)d_in[6];
    const float* tfw1 = (const float*)d_in[7];
    const float* tfb1 = (const float*)d_in[8];
    const float* tfw2 = (const float*)d_in[9];
    const float* tfb2 = (const float*)d_in[10];
    const float* tfw3 = (const float*)d_in[11];
    const float* tfb3 = (const float*)d_in[12];
    const float* w1   = (const float*)d_in[13];
    const float* w2   = (const float*)d_in[14];
    const float* w3   = (const float*)d_in[15];
    const float* w4   = (const float*)d_in[16];
    const float* g1   = (const float*)d_in[17];
    const float* be1  = (const float*)d_in[18];
    const float* g2   = (const float*)d_in[19];
    const float* be2  = (const float*)d_in[20];
    const float* g3   = (const float*)d_in[21];
    const float* be3  = (const float*)d_in[22];
    const float* g4   = (const float*)d_in[23];
    const float* be4  = (const float*)d_in[24];

    char* wsb = (char*)d_ws;
    size_t off = 0;
    auto alloc = [&](size_t bytes) -> void* {
        void* p = wsb + off;
        off = (off + bytes + 255) & ~(size_t)255;
        return p;
    };
    u64* s1b   = (u64*)alloc(sizeof(u64)*(size_t)TT*BB*NN);
    u64* s2b   = (u64*)alloc(sizeof(u64)*(size_t)TT*BB*NN*2);
    u32* mx    = (u32*)alloc(sizeof(u32)*(size_t)TT*BB*1024);
    u32* mx4   = (u32*)alloc(sizeof(u32)*(size_t)TT*BB*1024);
    float* trs = (float*)alloc(sizeof(float)*BB*9);
    float* xa  = (float*)alloc(sizeof(float)*(size_t)BB*14*NN);
    float4* xa4 = (float4*)alloc(sizeof(float4)*(size_t)BB*NN);
    int* idx   = (int*)alloc(sizeof(int)*(size_t)BB*NN*KNB);
    float* z1  = (float*)alloc(sizeof(float)*(size_t)BB*64*PP);
    float* part1 = (float*)alloc(sizeof(float)*(size_t)1024*64*2);
    float* st1 = (float*)alloc(sizeof(float)*64*2);
    float* st2 = (float*)alloc(sizeof(float)*512*2);
    float* st3 = (float*)alloc(sizeof(float)*1024*2);
    float* st4 = (float*)alloc(sizeof(float)*4096*2);
    float* h1v = (float*)alloc(sizeof(float)*(size_t)TT*BB*512);
    float* h2v = (float*)alloc(sizeof(float)*(size_t)TT*BB*256);
    u64* h1b = (u64*)alloc(sizeof(u64)*(size_t)TT*BB*64*512);
    u64* h1n = (u64*)alloc(sizeof(u64)*(size_t)TT*BB*PP);
    u16* m2p = (u16*)alloc(sizeof(u16)*(size_t)TT*BB*NN*128);
    u16* h3p = (u16*)alloc(sizeof(u16)*(size_t)TT*BB*NN*256);
    u64* m2b = (u64*)alloc(sizeof(u64)*(size_t)TT*BB*128*32);
    u64* h3b = (u64*)alloc(sizeof(u64)*(size_t)TT*BB*256*32);
    int* Mi64  = (int*)alloc(sizeof(int)*(size_t)TT*64*64);
    int* Mi128 = (int*)alloc(sizeof(int)*(size_t)TT*128*128);
    int* Mi256 = (int*)alloc(sizeof(int)*(size_t)TT*256*256);
    short* wp2h = (short*)alloc(sizeof(short)*(size_t)128*64);
    short* wp2m = (short*)alloc(sizeof(short)*(size_t)128*64);
    short* wp2l = (short*)alloc(sizeof(short)*(size_t)128*64);
    short* wp3h = (short*)alloc(sizeof(short)*(size_t)256*128);
    short* wp3m = (short*)alloc(sizeof(short)*(size_t)256*128);
    short* wp3l = (short*)alloc(sizeof(short)*(size_t)256*128);
    short* wp4h = (short*)alloc(sizeof(short)*(size_t)1024*256);
    short* wp4m = (short*)alloc(sizeof(short)*(size_t)1024*256);
    short* wp4l = (short*)alloc(sizeof(short)*(size_t)1024*256);
    short* wpth = (short*)alloc(sizeof(short)*(size_t)1024*128);
    short* wptm = (short*)alloc(sizeof(short)*(size_t)1024*128);
    short* wptl = (short*)alloc(sizeof(short)*(size_t)1024*128);
    if (off > ws_size) return;

    hipMemsetAsync(mx, 0, sizeof(u32)*(size_t)TT*BB*1024, stream);
    hipMemsetAsync(mx4, 0, sizeof(u32)*(size_t)TT*BB*1024, stream);
    hipMemsetAsync(Mi64, 0, sizeof(int)*(size_t)TT*64*64, stream);
    hipMemsetAsync(Mi128, 0, sizeof(int)*(size_t)TT*128*128, stream);
    hipMemsetAsync(Mi256, 0, sizeof(int)*(size_t)TT*256*256, stream);

    // weight prep (exact 3-way bf16 split)
    k_wprep<<<dim3((128*64+255)/256), dim3(256), 0, stream>>>(w2, wp2h, wp2m, wp2l, 128, 64);
    k_wprep<<<dim3((256*128+255)/256), dim3(256), 0, stream>>>(w3, wp3h, wp3m, wp3l, 256, 128);
    k_wprep<<<dim3((1024*256+255)/256), dim3(256), 0, stream>>>(w4, wp4h, wp4m, wp4l, 1024, 256);
    k_wprep<<<dim3((1024*128+255)/256), dim3(256), 0, stream>>>(tw3, wpth, wptm, wptl, 1024, 128);

    // T-Net
    k_tnet1<<<dim3(64), dim3(256), 0, stream>>>(x, tw1, tb1, s1b);
    k_tnet2<<<dim3(64, 4), dim3(256), 0, stream>>>(s1b, tw2, tb2, (u32*)s2b);
    k_mconv<128,1024,0,true><<<dim3(16,16,8), dim3(256), 0, stream>>>(
        s2b, wpth, wptm, wptl, nullptr, nullptr, nullptr, tb3, nullptr, mx, NN);
    k_fc1<<<dim3(512, 8), dim3(64), 0, stream>>>(mx, tfw1, tfb1, h1v);
    k_fc2<<<dim3(256, 8), dim3(64), 0, stream>>>(h1v, tfw2, tfb2, h2v);
    k_fc3<<<dim3(8), dim3(64), 0, stream>>>(h2v, tfw3, tfb3, trs);
    k_trans<<<dim3(64), dim3(256), 0, stream>>>(x, trs, xa, xa4);
    // KNN (wave-per-query)
    k_knn<<<dim3(NN/4, BB), dim3(256), 0, stream>>>(xa4, idx);
    // fused graph-feature + edge conv1 GEMM (z once) + stats partials
    k_zstats<<<dim3(128, 8), dim3(256), 0, stream>>>(xa, idx, w1, part1, z1);
    k_reduce<<<dim3(64), dim3(256), 0, stream>>>(part1, st1, 64, 1024, 262144.0);
    k_h1<<<dim3(128, 8), dim3(256), 0, stream>>>(z1, st1, g1, be1, h1b, h1n);
    // edge conv2: stats via tiled Gram, apply via MFMA (+ max over k)
    k_gram_h1<<<dim3(8, TT*BB), dim3(256), 0, stream>>>(h1b, Mi64);
    k_proj<64><<<dim3(128, TT), dim3(64), 0, stream>>>(Mi64, w2, st2, 128, 262144.0);
    k_mconv<64,128,3,true><<<dim3(PP/128,2,8), dim3(256), 0, stream>>>(
        h1n, wp2h, wp2m, wp2l, st2, g2, be2, nullptr, m2p, nullptr, PP);
    k_repack<128><<<dim3(32,8,4), dim3(256), 0, stream>>>(m2p, m2b);
    // conv3
    k_gram2<128><<<dim3(2,2,TT*BB), dim3(256), 0, stream>>>(m2b, Mi128);
    k_proj<128><<<dim3(256, TT), dim3(128), 0, stream>>>(Mi128, w3, st3, 256, 16384.0);
    k_mconv<128,256,1,false><<<dim3(16,4,8), dim3(256), 0, stream>>>(
        m2p, wp3h, wp3m, wp3l, st3, g3, be3, nullptr, h3p, nullptr, NN);
    k_repack<256><<<dim3(32,8,4), dim3(256), 0, stream>>>(h3p, h3b);
    // conv4
    k_gram2<256><<<dim3(4,4,TT*BB), dim3(256), 0, stream>>>(h3b, Mi256);
    k_proj<256><<<dim3(1024, TT), dim3(256), 0, stream>>>(Mi256, w4, st4, 1024, 16384.0);
    k_mconv<256,1024,2,false><<<dim3(16,16,8), dim3(256), 0, stream>>>(
        h3p, wp4h, wp4m, wp4l, st4, g4, be4, nullptr, nullptr, mx4, NN);
    // output
    k_out<<<dim3(32), dim3(256), 0, stream>>>(mx4, (float*)d_out);
}

// Round 10
// 768.680 us; speedup vs baseline: 1.0485x; 1.0485x over previous
//
#include <hip/hip_runtime.h>
#include <stdint.h>

#define TT 4
#define BB 8
#define NN 2048
#define KNB 16
#define PP (NN*KNB)
#define VTH 1.0f
#define EPSB 1e-5f

typedef unsigned long long u64;
typedef unsigned int u32;
typedef unsigned short u16;
typedef unsigned char u8;
typedef __attribute__((ext_vector_type(8))) short short8;
typedef __attribute__((ext_vector_type(4))) float f4;

#define GLOAD_LDS16(g, l) __builtin_amdgcn_global_load_lds( \
    (const __attribute__((address_space(1))) u32*)(g), \
    (__attribute__((address_space(3))) u32*)(l), 16, 0, 0)

__device__ __forceinline__ float lif_step(float& v, float x) {
    v = v + (x - v) / 2.0f;
    float s = (v - VTH >= 0.0f) ? 1.0f : 0.0f;
    v = v * (1.0f - s);
    return s;
}

// ---------------- T-Net ----------------
__global__ __launch_bounds__(256) void k_tnet1(const float* __restrict__ x, const float* __restrict__ w,
        const float* __restrict__ bi, u64* __restrict__ s1b) {
    int i = blockIdx.x*256 + threadIdx.x;
    int b = i >> 11, n = i & 2047;
    float p0 = x[((size_t)b*14+0)*NN+n];
    float p1 = x[((size_t)b*14+1)*NN+n];
    float p2 = x[((size_t)b*14+2)*NN+n];
    u64 m[TT] = {0,0,0,0};
    for (int d = 0; d < 64; ++d) {
        float z = ((w[d*3+0]*p0 + w[d*3+1]*p1) + w[d*3+2]*p2) + bi[d];
        float v = 0.f;
        #pragma unroll
        for (int t = 0; t < TT; ++t) {
            float s = lif_step(v, z);
            if (s != 0.f) m[t] |= (1ull << d);
        }
    }
    #pragma unroll
    for (int t = 0; t < TT; ++t) s1b[((size_t)t*BB + b)*NN + n] = m[t];
}

// conv2: 64->128, split over 4 channel-chunks of 32 for occupancy
__global__ __launch_bounds__(256) void k_tnet2(const u64* __restrict__ s1b, const float* __restrict__ w,
        const float* __restrict__ bi, u32* __restrict__ s2b32) {
    __shared__ float ws[32*64];
    int tid = threadIdx.x;
    int ec = blockIdx.y;
    for (int l = tid; l < 32*64; l += 256) ws[l] = w[ec*32*64 + l];
    __syncthreads();
    int i = blockIdx.x*256 + tid;
    int b = i >> 11, n = i & 2047;
    u64 m[TT];
    #pragma unroll
    for (int t = 0; t < TT; ++t) m[t] = s1b[((size_t)t*BB+b)*NN+n];
    u32 o[TT] = {0,0,0,0};
    for (int el = 0; el < 32; ++el) {
        float z[TT] = {0.f,0.f,0.f,0.f};
        #pragma unroll 8
        for (int d = 0; d < 64; ++d) {
            float wv = ws[el*64+d];
            #pragma unroll
            for (int t = 0; t < TT; ++t) z[t] += ((m[t]>>d)&1ull) ? wv : 0.f;
        }
        float v = 0.f, bb = bi[ec*32 + el];
        #pragma unroll
        for (int t = 0; t < TT; ++t) {
            float s = lif_step(v, z[t] + bb);
            if (s != 0.f) o[t] |= (1u << el);
        }
    }
    #pragma unroll
    for (int t = 0; t < TT; ++t)
        s2b32[(((size_t)t*BB+b)*NN+n)*4 + ec] = o[t];
}

// FC head, wave-parallel
__global__ __launch_bounds__(64) void k_fc1(const u32* __restrict__ mx, const float* __restrict__ fw1,
        const float* __restrict__ fb1, float* __restrict__ h1v) {
    int f = blockIdx.x, b = blockIdx.y, lane = threadIdx.x;
    float wr[16];
    #pragma unroll
    for (int j = 0; j < 16; ++j) wr[j] = fw1[(size_t)f*1024 + j*64 + lane];
    float z[TT];
    #pragma unroll
    for (int t = 0; t < TT; ++t) {
        float s = 0.f;
        #pragma unroll
        for (int j = 0; j < 16; ++j)
            s += wr[j] * (float)mx[((size_t)t*BB+b)*1024 + j*64 + lane];
        #pragma unroll
        for (int o = 1; o < 64; o <<= 1) s += __shfl_xor(s, o, 64);
        z[t] = s;
    }
    if (lane == 0) {
        float v = 0.f;
        #pragma unroll
        for (int t = 0; t < TT; ++t)
            h1v[((size_t)t*BB+b)*512 + f] = lif_step(v, z[t] + fb1[f]);
    }
}

__global__ __launch_bounds__(64) void k_fc2(const float* __restrict__ h1v, const float* __restrict__ fw2,
        const float* __restrict__ fb2, float* __restrict__ h2v) {
    int f = blockIdx.x, b = blockIdx.y, lane = threadIdx.x;
    float wr[8];
    #pragma unroll
    for (int j = 0; j < 8; ++j) wr[j] = fw2[(size_t)f*512 + j*64 + lane];
    float z[TT];
    #pragma unroll
    for (int t = 0; t < TT; ++t) {
        float s = 0.f;
        #pragma unroll
        for (int j = 0; j < 8; ++j)
            s += wr[j] * h1v[((size_t)t*BB+b)*512 + j*64 + lane];
        #pragma unroll
        for (int o = 1; o < 64; o <<= 1) s += __shfl_xor(s, o, 64);
        z[t] = s;
    }
    if (lane == 0) {
        float v = 0.f;
        #pragma unroll
        for (int t = 0; t < TT; ++t)
            h2v[((size_t)t*BB+b)*256 + f] = lif_step(v, z[t] + fb2[f]);
    }
}

__global__ __launch_bounds__(64) void k_fc3(const float* __restrict__ h2v, const float* __restrict__ fw3,
        const float* __restrict__ fb3, float* __restrict__ trans) {
    __shared__ float h3s[TT][9];
    int b = blockIdx.x, tid = threadIdx.x;
    if (tid < TT*9) {
        int t = tid/9, oo = tid%9;
        float z = 0.f;
        for (int c = 0; c < 256; ++c) z += fw3[oo*256+c]*h2v[((size_t)t*BB+b)*256 + c];
        h3s[t][oo] = z + fb3[oo];
    }
    __syncthreads();
    if (tid < 9) {
        float m = ((h3s[0][tid]+h3s[1][tid]) + (h3s[2][tid]+h3s[3][tid])) * 0.25f;
        int c = tid/3, dd = tid%3;
        trans[b*9+tid] = m + ((c==dd)?1.0f:0.0f);
    }
}

// apply transform; also emit packed float4 (x,y,z,sq) for KNN
__global__ __launch_bounds__(256) void k_trans(const float* __restrict__ x, const float* __restrict__ tr,
        float* __restrict__ xa, float4* __restrict__ xa4) {
    int i = blockIdx.x*256 + threadIdx.x;
    int b = i >> 11, n = i & 2047;
    float p0 = x[((size_t)b*14+0)*NN+n];
    float p1 = x[((size_t)b*14+1)*NN+n];
    float p2 = x[((size_t)b*14+2)*NN+n];
    const float* tb = tr + b*9;
    float a0 = (p0*tb[0] + p1*tb[3]) + p2*tb[6];
    float a1 = (p0*tb[1] + p1*tb[4]) + p2*tb[7];
    float a2 = (p0*tb[2] + p1*tb[5]) + p2*tb[8];
    xa[((size_t)b*14+0)*NN+n] = a0;
    xa[((size_t)b*14+1)*NN+n] = a1;
    xa[((size_t)b*14+2)*NN+n] = a2;
    for (int c = 3; c < 14; ++c) xa[((size_t)b*14+c)*NN+n] = x[((size_t)b*14+c)*NN+n];
    float4 p;
    p.x = a0; p.y = a1; p.z = a2;
    p.w = (a0*a0 + a1*a1) + a2*a2;
    xa4[(size_t)b*NN+n] = p;
}

// KNN: one wave per query point
__global__ __launch_bounds__(256) void k_knn(const float4* __restrict__ xa4, int* __restrict__ idx) {
    int wave = threadIdx.x >> 6, lane = threadIdx.x & 63;
    int b = blockIdx.y;
    int n = blockIdx.x*4 + wave;
    const float4* P = xa4 + (size_t)b*NN;
    float4 q = P[n];
    float sn = q.w;
    float vals[32];
    #pragma unroll
    for (int j = 0; j < 32; ++j) {
        float4 p = P[j*64 + lane];
        float inner = (q.x*p.x + q.y*p.y) + q.z*p.z;
        vals[j] = (2.0f*inner - sn) - p.w;
    }
    for (int k = 0; k < KNB; ++k) {
        float bv = -3.4e38f; int bj = 0;
        #pragma unroll
        for (int j = 0; j < 32; ++j) if (vals[j] > bv) { bv = vals[j]; bj = j; }
        int bm = bj*64 + lane;
        u32 fb = __float_as_uint(bv);
        fb = (fb & 0x80000000u) ? ~fb : (fb | 0x80000000u);
        u64 key = ((u64)fb << 32) | (u32)(~bm);
        #pragma unroll
        for (int o2 = 1; o2 < 64; o2 <<= 1) {
            u64 other = __shfl_xor(key, o2, 64);
            key = (other > key) ? other : key;
        }
        int wm = (int)(~(u32)key);
        if (lane == 0) idx[((size_t)b*NN + n)*KNB + k] = wm;
        int wl = wm & 63, wj = wm >> 6;
        if (lane == wl) {
            #pragma unroll
            for (int j = 0; j < 32; ++j) if (j == wj) vals[j] = -3.4e38f;
        }
    }
}

// fused graph-feature + edge conv1 GEMM: z once + stats partials (bit-identical z)
__global__ __launch_bounds__(256) void k_zstats(const float* __restrict__ xa, const int* __restrict__ idx,
        const float* __restrict__ w1, float* __restrict__ part1, float* __restrict__ z1) {
    __shared__ float w1s[64*28];
    __shared__ float wsum[4][64], wsq[4][64];
    int pt = blockIdx.x, b = blockIdx.y;
    int p0 = pt*256, tid = threadIdx.x;
    int p = p0 + tid;
    for (int l = tid; l < 64*28; l += 256) w1s[l] = w1[l];
    __syncthreads();
    int n = p >> 4;
    int mm = idx[((size_t)b*NN+n)*KNB + (p & 15)];
    float gr[28];
    #pragma unroll
    for (int c = 0; c < 14; ++c) {
        float ctr = xa[((size_t)b*14+c)*NN + n];
        float nb  = xa[((size_t)b*14+c)*NN + mm];
        gr[c] = ctr;
        gr[14+c] = nb - ctr;
    }
    int wv = tid>>6, lane = tid&63;
    for (int d = 0; d < 64; ++d) {
        float z = 0.f;
        #pragma unroll
        for (int c = 0; c < 28; ++c) z += w1s[d*28+c]*gr[c];
        z1[((size_t)b*64+d)*PP + p] = z;
        float s = z, q = z*z;
        #pragma unroll
        for (int o = 1; o < 64; o <<= 1) { s += __shfl_xor(s, o, 64); q += __shfl_xor(q, o, 64); }
        if (lane == 0) { wsum[wv][d] = s; wsq[wv][d] = q; }
    }
    __syncthreads();
    if (tid < 64) {
        float s = (wsum[0][tid]+wsum[1][tid])+(wsum[2][tid]+wsum[3][tid]);
        float q = (wsq[0][tid]+wsq[1][tid])+(wsq[2][tid]+wsq[3][tid]);
        size_t blk = (size_t)b*128 + pt;
        part1[(blk*64 + tid)*2+0] = s;
        part1[(blk*64 + tid)*2+1] = q;
    }
}

__global__ __launch_bounds__(256) void k_reduce(const float* __restrict__ part, float* __restrict__ stats, int nch, int nblk, double M) {
    __shared__ double sred[256], qred[256];
    int ch = blockIdx.x, tid = threadIdx.x;
    double s = 0.0, q = 0.0;
    for (int i = tid; i < nblk; i += 256) {
        s += (double)part[((size_t)i*nch + ch)*2 + 0];
        q += (double)part[((size_t)i*nch + ch)*2 + 1];
    }
    sred[tid] = s; qred[tid] = q;
    __syncthreads();
    for (int off = 128; off > 0; off >>= 1) {
        if (tid < off) { sred[tid] += sred[tid+off]; qred[tid] += qred[tid+off]; }
        __syncthreads();
    }
    if (tid == 0) {
        double mu = sred[0] / M;
        double var = qred[0] / M - mu*mu;
        if (var < 0.0) var = 0.0;
        stats[ch*2+0] = (float)mu;
        stats[ch*2+1] = 1.0f / sqrtf((float)var + EPSB);
    }
}

// edge conv1 apply from stored z1
__global__ __launch_bounds__(256) void k_h1(const float* __restrict__ z1,
        const float* __restrict__ st1, const float* __restrict__ g1, const float* __restrict__ be1,
        u64* __restrict__ h1b, u64* __restrict__ h1n) {
    int tid = threadIdx.x;
    int b = blockIdx.y;
    int p0 = blockIdx.x*256;
    int p = p0 + tid;
    int wordbase = (p0>>6) + (tid>>6);
    u64 pm[TT] = {0,0,0,0};
    for (int d = 0; d < 64; ++d) {
        float z = z1[((size_t)b*64+d)*PP + p];
        float mu = st1[d*2+0], iv = st1[d*2+1];
        float v = 0.f;
        #pragma unroll
        for (int t = 0; t < TT; ++t) {
            float y = (z - mu) * iv * g1[t*64+d] + be1[t*64+d];
            float s = lif_step(v, y);
            u64 m = __ballot(s != 0.f);
            if ((tid & 63) == 0) h1b[((size_t)(t*BB+b)*64 + d)*512 + wordbase] = m;
            pm[t] |= ((u64)(s != 0.f)) << d;
        }
    }
    #pragma unroll
    for (int t = 0; t < TT; ++t) h1n[(size_t)(t*BB+b)*PP + p] = pm[t];
}

// ---------------- Tiled popcount Grams (exact int counts) ----------------
__global__ __launch_bounds__(256) void k_gram_h1(const u64* __restrict__ h1b, int* __restrict__ Mi) {
    __shared__ u64 tw[64*65];
    int tid = threadIdx.x;
    int w0 = blockIdx.x*64;
    int tb = blockIdx.y;
    int t = tb >> 3;
    const u64* src = h1b + (size_t)tb*64*512;
    for (int l = tid; l < 64*64; l += 256) {
        int c = l >> 6, w = l & 63;
        tw[c*65+w] = src[(size_t)c*512 + w0 + w];
    }
    __syncthreads();
    int q = tid >> 4, r = tid & 15;
    int acc[4][4];
    #pragma unroll
    for (int i=0;i<4;++i)
        #pragma unroll
        for (int j=0;j<4;++j) acc[i][j]=0;
    #pragma unroll 4
    for (int w = 0; w < 64; ++w) {
        u64 av[4], bv[4];
        #pragma unroll
        for (int i=0;i<4;++i) av[i] = tw[(q+16*i)*65+w];
        #pragma unroll
        for (int j=0;j<4;++j) bv[j] = tw[(r+16*j)*65+w];
        #pragma unroll
        for (int i=0;i<4;++i)
            #pragma unroll
            for (int j=0;j<4;++j) acc[i][j] += (int)__popcll(av[i]&bv[j]);
    }
    #pragma unroll
    for (int i=0;i<4;++i)
        #pragma unroll
        for (int j=0;j<4;++j)
            atomicAdd(&Mi[((size_t)t*64 + q+16*i)*64 + r+16*j], acc[i][j]);
}

template<int C>
__global__ __launch_bounds__(256) void k_gram2(const u64* __restrict__ bits, int* __restrict__ Mi) {
    __shared__ u64 ta[64*33], tbt[64*33];
    int tid = threadIdx.x;
    int ci0 = blockIdx.x*64, cj0 = blockIdx.y*64;
    int tb = blockIdx.z;
    int t = tb >> 3;
    const u64* srcA = bits + ((size_t)tb*C + ci0)*32;
    const u64* srcB = bits + ((size_t)tb*C + cj0)*32;
    for (int l = tid; l < 64*32; l += 256) {
        int rr = l >> 5, w = l & 31;
        ta[rr*33+w]  = srcA[(size_t)rr*32+w];
        tbt[rr*33+w] = srcB[(size_t)rr*32+w];
    }
    __syncthreads();
    int q = tid >> 4, r = tid & 15;
    int acc[4][4];
    #pragma unroll
    for (int i=0;i<4;++i)
        #pragma unroll
        for (int j=0;j<4;++j) acc[i][j]=0;
    #pragma unroll 4
    for (int w = 0; w < 32; ++w) {
        u64 av[4], bv[4];
        #pragma unroll
        for (int i=0;i<4;++i) av[i] = ta[(q+16*i)*33+w];
        #pragma unroll
        for (int j=0;j<4;++j) bv[j] = tbt[(r+16*j)*33+w];
        #pragma unroll
        for (int i=0;i<4;++i)
            #pragma unroll
            for (int j=0;j<4;++j) acc[i][j] += (int)__popcll(av[i]&bv[j]);
    }
    #pragma unroll
    for (int i=0;i<4;++i)
        #pragma unroll
        for (int j=0;j<4;++j)
            atomicAdd(&Mi[((size_t)t*C + ci0+q+16*i)*C + cj0+r+16*j], acc[i][j]);
}

// project int Gram through weights -> per-(t,ch) (mean, inv_std)
template<int CIN>
__global__ void k_proj(const int* __restrict__ Mf, const float* __restrict__ w,
        float* __restrict__ st, int COUT, double cnt) {
    __shared__ double z2s[256], mns[256];
    int ch = blockIdx.x, t = blockIdx.y, c2 = threadIdx.x;
    const int* Mt = Mf + (size_t)t*CIN*CIN;
    double y = 0.0;
    for (int c = 0; c < CIN; ++c)
        y += (double)w[(size_t)ch*CIN+c] * (double)Mt[(size_t)c*CIN + c2];
    double wc2 = (double)w[(size_t)ch*CIN+c2];
    z2s[c2] = wc2 * y;
    mns[c2] = wc2 * (double)Mt[(size_t)c2*CIN + c2];
    __syncthreads();
    for (int off = CIN>>1; off > 0; off >>= 1) {
        if (c2 < off) { z2s[c2] += z2s[c2+off]; mns[c2] += mns[c2+off]; }
        __syncthreads();
    }
    if (c2 == 0) {
        double mu = mns[0] / cnt;
        double var = z2s[0] / cnt - mu*mu;
        if (var < 0.0) var = 0.0;
        st[((size_t)t*COUT+ch)*2+0] = (float)mu;
        st[((size_t)t*COUT+ch)*2+1] = 1.0f / sqrtf((float)var + EPSB);
    }
}

// weight prep: fp32 w[F][K] -> exact 3-way bf16 split in MFMA-frag layout [K/8][F][8]
__global__ __launch_bounds__(256) void k_wprep(const float* __restrict__ w,
        short* __restrict__ hi, short* __restrict__ mid, short* __restrict__ lo, int F, int K) {
    int i = blockIdx.x*256 + threadIdx.x;
    if (i >= F*K) return;
    int f = i / K, k = i % K;
    float wv = w[i];
    u32 b0 = __float_as_uint(wv);
    float h = __uint_as_float(b0 & 0xFFFF0000u);
    float r1 = wv - h;
    u32 b1 = __float_as_uint(r1);
    float m = __uint_as_float(b1 & 0xFFFF0000u);
    float r2 = r1 - m;
    u32 b2 = __float_as_uint(r2);
    size_t o = ((size_t)(k>>3)*F + f)*8 + (k&7);
    hi[o]  = (short)(b0 >> 16);
    mid[o] = (short)(b1 >> 16);
    lo[o]  = (short)(b2 >> 16);
}

// ---------------- MFMA spike conv: 16 rows/wave, double-buffered KT=32 weight tiles ----------------
// Per 32-k tile: issue next tile's global_load_lds BEFORE the 48 MFMAs, one barrier per tile.
// Load latency hides under the MFMA chain (T3-minimum-2-phase). k-order unchanged -> bit-identical.
template<int K, int F, int MODE, bool BITS>
__global__ __launch_bounds__(256) void k_mconv(
        const void* __restrict__ Asrc,
        const short* __restrict__ Whi, const short* __restrict__ Wmd, const short* __restrict__ Wlo,
        const float* __restrict__ st, const float* __restrict__ ga, const float* __restrict__ be,
        const float* __restrict__ bias,
        u16* __restrict__ outp, u32* __restrict__ outm, int NPTS) {
    constexpr int NT = K/32;                // 32-k tiles
    constexpr int NW = (K+63)/64;
    __shared__ short wsm[2][12*512];        // 2 x 12KB: rows [kq(4)][split(3)][64f][8]
    __shared__ short sptab[BITS ? 256*8 : 8];
    __shared__ u32 morr[TT][64];
    int tid = threadIdx.x;
    int wave = tid >> 6, lane = tid & 63;
    int l15 = lane & 15, lg = lane >> 4;
    int b = blockIdx.z;
    int n_base = blockIdx.x*64 + wave*16;
    int f0 = blockIdx.y*64;
    if (MODE == 0 || MODE == 2)
        for (int l = tid; l < TT*64; l += 256) morr[l>>6][l&63] = 0u;
    if (BITS) {
        #pragma unroll
        for (int j = 0; j < 8; ++j) sptab[tid*8+j] = (short)(((tid>>j)&1) * 0x3F80);
    }

    f4 acc[4][TT];
    #pragma unroll
    for (int i = 0; i < 4; ++i)
        #pragma unroll
        for (int t = 0; t < TT; ++t) acc[i][t] = (f4)0.f;

    u64 aw[TT][NW];
    const u16* Au[TT];
    #pragma unroll
    for (int t = 0; t < TT; ++t) {
        if (BITS) {
            const u64* Ab = (const u64*)Asrc + ((size_t)(t*BB+b)*NPTS + n_base + l15)*NW;
            #pragma unroll
            for (int wq = 0; wq < NW; ++wq) aw[t][wq] = Ab[wq];
        } else {
            Au[t] = (const u16*)Asrc + ((size_t)(t*BB+b)*NPTS + n_base + l15)*K + lg*8;
        }
    }
    const short* Wsrc[3] = {Whi, Wmd, Wlo};

    // stage tile kt (4 kq-rows x 3 splits = 12 rows, 3 GLOADs/wave)
    auto stage = [&](int buf, int kt) {
        #pragma unroll
        for (int r = wave; r < 12; r += 4) {
            int kq = r/3, s = r - kq*3;
            const short* g = Wsrc[s] + ((size_t)(kt*4 + kq)*F + f0)*8 + lane*8;
            GLOAD_LDS16(g, &wsm[buf][r*512]);
        }
    };

    stage(0, 0);
    __syncthreads();
    #pragma unroll
    for (int kt = 0; kt < NT; ++kt) {
        int cur = kt & 1;
        if (kt + 1 < NT) stage(cur ^ 1, kt + 1);   // issue-early: flies during MFMA below
        int kg = kt*32;
        short8 a[TT];
        #pragma unroll
        for (int t = 0; t < TT; ++t) {
            if (BITS) {
                u32 byte = (u32)(aw[t][kg>>6] >> ((kg&63) + lg*8)) & 0xFFu;
                a[t] = *(const short8*)(sptab + byte*8);
            } else {
                a[t] = *(const short8*)(Au[t] + kg);
            }
        }
        #pragma unroll
        for (int fs = 0; fs < 4; ++fs) {
            const short* base = &wsm[cur][lg*1536 + (fs*16+l15)*8];
            short8 whi = *(const short8*)(base);
            short8 wmd = *(const short8*)(base + 512);
            short8 wlo = *(const short8*)(base + 1024);
            #pragma unroll
            for (int t = 0; t < TT; ++t) {
                acc[fs][t] = __builtin_amdgcn_mfma_f32_16x16x32_bf16(a[t], whi, acc[fs][t], 0, 0, 0);
                acc[fs][t] = __builtin_amdgcn_mfma_f32_16x16x32_bf16(a[t], wmd, acc[fs][t], 0, 0, 0);
                acc[fs][t] = __builtin_amdgcn_mfma_f32_16x16x32_bf16(a[t], wlo, acc[fs][t], 0, 0, 0);
            }
        }
        __syncthreads();   // drains staged loads; next tile ready, cur free for overwrite
    }
    // epilogue: D row = n_base + lg*4 + reg, col f = f0 + fs*16 + l15
    if (MODE == 1) {
        #pragma unroll
        for (int fs = 0; fs < 4; ++fs) {
            int f = f0 + fs*16 + l15;
            #pragma unroll
            for (int reg = 0; reg < 4; ++reg) {
                int n = n_base + lg*4 + reg;
                float v = 0.f;
                #pragma unroll
                for (int t = 0; t < TT; ++t) {
                    int ch = t*F + f;
                    float y = (acc[fs][t][reg] - st[(size_t)ch*2+0])*st[(size_t)ch*2+1]*ga[ch] + be[ch];
                    float s = lif_step(v, y);
                    outp[((size_t)(t*BB+b)*NPTS + n)*F + f] = (s != 0.f) ? (u16)0x3F80 : (u16)0;
                }
            }
        }
    } else if (MODE == 3) {
        #pragma unroll
        for (int fs = 0; fs < 4; ++fs) {
            int f = f0 + fs*16 + l15;
            u32 nib = 0u;
            #pragma unroll
            for (int reg = 0; reg < 4; ++reg) {
                float v = 0.f;
                #pragma unroll
                for (int t = 0; t < TT; ++t) {
                    int ch = t*F + f;
                    float y = (acc[fs][t][reg] - st[(size_t)ch*2+0])*st[(size_t)ch*2+1]*ga[ch] + be[ch];
                    float s = lif_step(v, y);
                    if (s != 0.f) nib |= (1u << t);
                }
            }
            nib |= __shfl_xor(nib, 16, 64);
            nib |= __shfl_xor(nib, 32, 64);
            if (lg == 0) {
                int n_pt = n_base >> 4;
                #pragma unroll
                for (int t = 0; t < TT; ++t)
                    outp[((size_t)(t*BB+b)*(NPTS>>4) + n_pt)*F + f] = ((nib>>t)&1u) ? (u16)0x3F80 : (u16)0;
            }
        }
    } else {
        #pragma unroll
        for (int fs = 0; fs < 4; ++fs) {
            int f = f0 + fs*16 + l15;
            u32 any[TT] = {0,0,0,0};
            float bb = (MODE == 0) ? bias[f] : 0.f;
            #pragma unroll
            for (int reg = 0; reg < 4; ++reg) {
                float v = 0.f;
                #pragma unroll
                for (int t = 0; t < TT; ++t) {
                    float y;
                    if (MODE == 0) y = acc[fs][t][reg] + bb;
                    else {
                        int ch = t*F + f;
                        y = (acc[fs][t][reg] - st[(size_t)ch*2+0])*st[(size_t)ch*2+1]*ga[ch] + be[ch];
                    }
                    float s = lif_step(v, y);
                    if (s != 0.f) any[t] = 1u;
                }
            }
            #pragma unroll
            for (int t = 0; t < TT; ++t) if (any[t]) atomicOr(&morr[t][fs*16+l15], 1u);
        }
        __syncthreads();
        for (int l = tid; l < TT*64; l += 256)
            if (morr[l>>6][l&63]) atomicOr(&outm[((size_t)((l>>6)*BB+b))*F + f0 + (l&63)], 1u);
    }
}

// repack point-major bf16-u16 spikes [t][b][n][C] -> channel-major bits [t][b][C][32 words over n]
template<int C>
__global__ __launch_bounds__(256) void k_repack(const u16* __restrict__ sp, u64* __restrict__ bits) {
    __shared__ u16 tile[64][C+2];
    int tid = threadIdx.x;
    int nw = blockIdx.x, b = blockIdx.y, t = blockIdx.z;
    const u16* src = sp + ((size_t)(t*BB+b)*NN + nw*64)*C;
    for (int i = tid*2; i < 64*C; i += 512) {
        u32 v = *(const u32*)(src + i);
        int r = i / C, c = i % C;
        *(u32*)&tile[r][c] = v;
    }
    __syncthreads();
    int wave = tid >> 6, lane = tid & 63;
    for (int c = wave; c < C; c += 4) {
        u64 m = __ballot(tile[lane][c] != 0);
        if (lane == 0) bits[((size_t)(t*BB+b)*C + c)*32 + nw] = m;
    }
}

__global__ __launch_bounds__(256) void k_out(const u32* __restrict__ mx4, float* __restrict__ out) {
    int i = blockIdx.x*256 + threadIdx.x;
    int b = i >> 10, g = i & 1023;
    float s = (float)(mx4[((size_t)0*BB+b)*1024+g] + mx4[((size_t)1*BB+b)*1024+g]
                    + mx4[((size_t)2*BB+b)*1024+g] + mx4[((size_t)3*BB+b)*1024+g]);
    out[i] = s * 0.25f;
}

extern "C" void kernel_launch(void* const* d_in, const int* in_sizes, int n_in,
                              void* d_out, int out_size, void* d_ws, size_t ws_size,
                              hipStream_t stream) {
    (void)in_sizes; (void)n_in; (void)out_size;
    const float* x    = (const float*)d_in[0];
    const float* tw1  = (const float*)d_in[1];
    const float* tb1  = (const float*)d_in[2];
    const float* tw2  = (const float*)d_in[3];
    const float* tb2  = (const float*)d_in[4];
    const float* tw3  = (const float*)d_in[5];
    const float* tb3  = (const float*)d_in[6];
    const float* tfw1 = (const float*)d_in[7];
    const float* tfb1 = (const float*)d_in[8];
    const float* tfw2 = (const float*)d_in[9];
    const float* tfb2 = (const float*)d_in[10];
    const float* tfw3 = (const float*)d_in[11];
    const float* tfb3 = (const float*)d_in[12];
    const float* w1   = (const float*)d_in[13];
    const float* w2   = (const float*)d_in[14];
    const float* w3   = (const float*)d_in[15];
    const float* w4   = (const float*)d_in[16];
    const float* g1   = (const float*)d_in[17];
    const float* be1  = (const float*)d_in[18];
    const float* g2   = (const float*)d_in[19];
    const float* be2  = (const float*)d_in[20];
    const float* g3   = (const float*)d_in[21];
    const float* be3  = (const float*)d_in[22];
    const float* g4   = (const float*)d_in[23];
    const float* be4  = (const float*)d_in[24];

    char* wsb = (char*)d_ws;
    size_t off = 0;
    auto alloc = [&](size_t bytes) -> void* {
        void* p = wsb + off;
        off = (off + bytes + 255) & ~(size_t)255;
        return p;
    };
    u64* s1b   = (u64*)alloc(sizeof(u64)*(size_t)TT*BB*NN);
    u64* s2b   = (u64*)alloc(sizeof(u64)*(size_t)TT*BB*NN*2);
    u32* mx    = (u32*)alloc(sizeof(u32)*(size_t)TT*BB*1024);
    u32* mx4   = (u32*)alloc(sizeof(u32)*(size_t)TT*BB*1024);
    float* trs = (float*)alloc(sizeof(float)*BB*9);
    float* xa  = (float*)alloc(sizeof(float)*(size_t)BB*14*NN);
    float4* xa4 = (float4*)alloc(sizeof(float4)*(size_t)BB*NN);
    int* idx   = (int*)alloc(sizeof(int)*(size_t)BB*NN*KNB);
    float* z1  = (float*)alloc(sizeof(float)*(size_t)BB*64*PP);
    float* part1 = (float*)alloc(sizeof(float)*(size_t)1024*64*2);
    float* st1 = (float*)alloc(sizeof(float)*64*2);
    float* st2 = (float*)alloc(sizeof(float)*512*2);
    float* st3 = (float*)alloc(sizeof(float)*1024*2);
    float* st4 = (float*)alloc(sizeof(float)*4096*2);
    float* h1v = (float*)alloc(sizeof(float)*(size_t)TT*BB*512);
    float* h2v = (float*)alloc(sizeof(float)*(size_t)TT*BB*256);
    u64* h1b = (u64*)alloc(sizeof(u64)*(size_t)TT*BB*64*512);
    u64* h1n = (u64*)alloc(sizeof(u64)*(size_t)TT*BB*PP);
    u16* m2p = (u16*)alloc(sizeof(u16)*(size_t)TT*BB*NN*128);
    u16* h3p = (u16*)alloc(sizeof(u16)*(size_t)TT*BB*NN*256);
    u64* m2b = (u64*)alloc(sizeof(u64)*(size_t)TT*BB*128*32);
    u64* h3b = (u64*)alloc(sizeof(u64)*(size_t)TT*BB*256*32);
    int* Mi64  = (int*)alloc(sizeof(int)*(size_t)TT*64*64);
    int* Mi128 = (int*)alloc(sizeof(int)*(size_t)TT*128*128);
    int* Mi256 = (int*)alloc(sizeof(int)*(size_t)TT*256*256);
    short* wp2h = (short*)alloc(sizeof(short)*(size_t)128*64);
    short* wp2m = (short*)alloc(sizeof(short)*(size_t)128*64);
    short* wp2l = (short*)alloc(sizeof(short)*(size_t)128*64);
    short* wp3h = (short*)alloc(sizeof(short)*(size_t)256*128);
    short* wp3m = (short*)alloc(sizeof(short)*(size_t)256*128);
    short* wp3l = (short*)alloc(sizeof(short)*(size_t)256*128);
    short* wp4h = (short*)alloc(sizeof(short)*(size_t)1024*256);
    short* wp4m = (short*)alloc(sizeof(short)*(size_t)1024*256);
    short* wp4l = (short*)alloc(sizeof(short)*(size_t)1024*256);
    short* wpth = (short*)alloc(sizeof(short)*(size_t)1024*128);
    short* wptm = (short*)alloc(sizeof(short)*(size_t)1024*128);
    short* wptl = (short*)alloc(sizeof(short)*(size_t)1024*128);
    if (off > ws_size) return;

    hipMemsetAsync(mx, 0, sizeof(u32)*(size_t)TT*BB*1024, stream);
    hipMemsetAsync(mx4, 0, sizeof(u32)*(size_t)TT*BB*1024, stream);
    hipMemsetAsync(Mi64, 0, sizeof(int)*(size_t)TT*64*64, stream);
    hipMemsetAsync(Mi128, 0, sizeof(int)*(size_t)TT*128*128, stream);
    hipMemsetAsync(Mi256, 0, sizeof(int)*(size_t)TT*256*256, stream);

    // weight prep (exact 3-way bf16 split)
    k_wprep<<<dim3((128*64+255)/256), dim3(256), 0, stream>>>(w2, wp2h, wp2m, wp2l, 128, 64);
    k_wprep<<<dim3((256*128+255)/256), dim3(256), 0, stream>>>(w3, wp3h, wp3m, wp3l, 256, 128);
    k_wprep<<<dim3((1024*256+255)/256), dim3(256), 0, stream>>>(w4, wp4h, wp4m, wp4l, 1024, 256);
    k_wprep<<<dim3((1024*128+255)/256), dim3(256), 0, stream>>>(tw3, wpth, wptm, wptl, 1024, 128);

    // T-Net
    k_tnet1<<<dim3(64), dim3(256), 0, stream>>>(x, tw1, tb1, s1b);
    k_tnet2<<<dim3(64, 4), dim3(256), 0, stream>>>(s1b, tw2, tb2, (u32*)s2b);
    k_mconv<128,1024,0,true><<<dim3(32,16,8), dim3(256), 0, stream>>>(
        s2b, wpth, wptm, wptl, nullptr, nullptr, nullptr, tb3, nullptr, mx, NN);
    k_fc1<<<dim3(512, 8), dim3(64), 0, stream>>>(mx, tfw1, tfb1, h1v);
    k_fc2<<<dim3(256, 8), dim3(64), 0, stream>>>(h1v, tfw2, tfb2, h2v);
    k_fc3<<<dim3(8), dim3(64), 0, stream>>>(h2v, tfw3, tfb3, trs);
    k_trans<<<dim3(64), dim3(256), 0, stream>>>(x, trs, xa, xa4);
    // KNN (wave-per-query)
    k_knn<<<dim3(NN/4, BB), dim3(256), 0, stream>>>(xa4, idx);
    // fused graph-feature + edge conv1 GEMM (z once) + stats partials
    k_zstats<<<dim3(128, 8), dim3(256), 0, stream>>>(xa, idx, w1, part1, z1);
    k_reduce<<<dim3(64), dim3(256), 0, stream>>>(part1, st1, 64, 1024, 262144.0);
    k_h1<<<dim3(128, 8), dim3(256), 0, stream>>>(z1, st1, g1, be1, h1b, h1n);
    // edge conv2: stats via tiled Gram, apply via MFMA (+ max over k)
    k_gram_h1<<<dim3(8, TT*BB), dim3(256), 0, stream>>>(h1b, Mi64);
    k_proj<64><<<dim3(128, TT), dim3(64), 0, stream>>>(Mi64, w2, st2, 128, 262144.0);
    k_mconv<64,128,3,true><<<dim3(PP/64,2,8), dim3(256), 0, stream>>>(
        h1n, wp2h, wp2m, wp2l, st2, g2, be2, nullptr, m2p, nullptr, PP);
    k_repack<128><<<dim3(32,8,4), dim3(256), 0, stream>>>(m2p, m2b);
    // conv3
    k_gram2<128><<<dim3(2,2,TT*BB), dim3(256), 0, stream>>>(m2b, Mi128);
    k_proj<128><<<dim3(256, TT), dim3(128), 0, stream>>>(Mi128, w3, st3, 256, 16384.0);
    k_mconv<128,256,1,false><<<dim3(32,4,8), dim3(256), 0, stream>>>(
        m2p, wp3h, wp3m, wp3l, st3, g3, be3, nullptr, h3p, nullptr, NN);
    k_repack<256><<<dim3(32,8,4), dim3(256), 0, stream>>>(h3p, h3b);
    // conv4
    k_gram2<256><<<dim3(4,4,TT*BB), dim3(256), 0, stream>>>(h3b, Mi256);
    k_proj<256><<<dim3(1024, TT), dim3(256), 0, stream>>>(Mi256, w4, st4, 1024, 16384.0);
    k_mconv<256,1024,2,false><<<dim3(32,16,8), dim3(256), 0, stream>>>(
        h3p, wp4h, wp4m, wp4l, st4, g4, be4, nullptr, nullptr, mx4, NN);
    // output
    k_out<<<dim3(32), dim3(256), 0, stream>>>(mx4, (float*)d_out);
}

// Round 11
// 763.035 us; speedup vs baseline: 1.0562x; 1.0074x over previous
//
#include <hip/hip_runtime.h>
#include <stdint.h>

#define TT 4
#define BB 8
#define NN 2048
#define KNB 16
#define PP (NN*KNB)
#define VTH 1.0f
#define EPSB 1e-5f

typedef unsigned long long u64;
typedef unsigned int u32;
typedef unsigned short u16;
typedef unsigned char u8;
typedef __attribute__((ext_vector_type(8))) short short8;
typedef __attribute__((ext_vector_type(4))) float f4;

#define GLOAD_LDS16(g, l) __builtin_amdgcn_global_load_lds( \
    (const __attribute__((address_space(1))) u32*)(g), \
    (__attribute__((address_space(3))) u32*)(l), 16, 0, 0)

__device__ __forceinline__ float lif_step(float& v, float x) {
    v = v + (x - v) / 2.0f;
    float s = (v - VTH >= 0.0f) ? 1.0f : 0.0f;
    v = v * (1.0f - s);
    return s;
}

// ---------------- T-Net ----------------
__global__ __launch_bounds__(256) void k_tnet1(const float* __restrict__ x, const float* __restrict__ w,
        const float* __restrict__ bi, u64* __restrict__ s1b) {
    int i = blockIdx.x*256 + threadIdx.x;
    int b = i >> 11, n = i & 2047;
    float p0 = x[((size_t)b*14+0)*NN+n];
    float p1 = x[((size_t)b*14+1)*NN+n];
    float p2 = x[((size_t)b*14+2)*NN+n];
    u64 m[TT] = {0,0,0,0};
    for (int d = 0; d < 64; ++d) {
        float z = ((w[d*3+0]*p0 + w[d*3+1]*p1) + w[d*3+2]*p2) + bi[d];
        float v = 0.f;
        #pragma unroll
        for (int t = 0; t < TT; ++t) {
            float s = lif_step(v, z);
            if (s != 0.f) m[t] |= (1ull << d);
        }
    }
    #pragma unroll
    for (int t = 0; t < TT; ++t) s1b[((size_t)t*BB + b)*NN + n] = m[t];
}

// conv2: 64->128, split over 4 channel-chunks of 32 for occupancy
__global__ __launch_bounds__(256) void k_tnet2(const u64* __restrict__ s1b, const float* __restrict__ w,
        const float* __restrict__ bi, u32* __restrict__ s2b32) {
    __shared__ float ws[32*64];
    int tid = threadIdx.x;
    int ec = blockIdx.y;
    for (int l = tid; l < 32*64; l += 256) ws[l] = w[ec*32*64 + l];
    __syncthreads();
    int i = blockIdx.x*256 + tid;
    int b = i >> 11, n = i & 2047;
    u64 m[TT];
    #pragma unroll
    for (int t = 0; t < TT; ++t) m[t] = s1b[((size_t)t*BB+b)*NN+n];
    u32 o[TT] = {0,0,0,0};
    for (int el = 0; el < 32; ++el) {
        float z[TT] = {0.f,0.f,0.f,0.f};
        #pragma unroll 8
        for (int d = 0; d < 64; ++d) {
            float wv = ws[el*64+d];
            #pragma unroll
            for (int t = 0; t < TT; ++t) z[t] += ((m[t]>>d)&1ull) ? wv : 0.f;
        }
        float v = 0.f, bb = bi[ec*32 + el];
        #pragma unroll
        for (int t = 0; t < TT; ++t) {
            float s = lif_step(v, z[t] + bb);
            if (s != 0.f) o[t] |= (1u << el);
        }
    }
    #pragma unroll
    for (int t = 0; t < TT; ++t)
        s2b32[(((size_t)t*BB+b)*NN+n)*4 + ec] = o[t];
}

// FC head, wave-parallel
__global__ __launch_bounds__(64) void k_fc1(const u32* __restrict__ mx, const float* __restrict__ fw1,
        const float* __restrict__ fb1, float* __restrict__ h1v) {
    int f = blockIdx.x, b = blockIdx.y, lane = threadIdx.x;
    float wr[16];
    #pragma unroll
    for (int j = 0; j < 16; ++j) wr[j] = fw1[(size_t)f*1024 + j*64 + lane];
    float z[TT];
    #pragma unroll
    for (int t = 0; t < TT; ++t) {
        float s = 0.f;
        #pragma unroll
        for (int j = 0; j < 16; ++j)
            s += wr[j] * (float)mx[((size_t)t*BB+b)*1024 + j*64 + lane];
        #pragma unroll
        for (int o = 1; o < 64; o <<= 1) s += __shfl_xor(s, o, 64);
        z[t] = s;
    }
    if (lane == 0) {
        float v = 0.f;
        #pragma unroll
        for (int t = 0; t < TT; ++t)
            h1v[((size_t)t*BB+b)*512 + f] = lif_step(v, z[t] + fb1[f]);
    }
}

__global__ __launch_bounds__(64) void k_fc2(const float* __restrict__ h1v, const float* __restrict__ fw2,
        const float* __restrict__ fb2, float* __restrict__ h2v) {
    int f = blockIdx.x, b = blockIdx.y, lane = threadIdx.x;
    float wr[8];
    #pragma unroll
    for (int j = 0; j < 8; ++j) wr[j] = fw2[(size_t)f*512 + j*64 + lane];
    float z[TT];
    #pragma unroll
    for (int t = 0; t < TT; ++t) {
        float s = 0.f;
        #pragma unroll
        for (int j = 0; j < 8; ++j)
            s += wr[j] * h1v[((size_t)t*BB+b)*512 + j*64 + lane];
        #pragma unroll
        for (int o = 1; o < 64; o <<= 1) s += __shfl_xor(s, o, 64);
        z[t] = s;
    }
    if (lane == 0) {
        float v = 0.f;
        #pragma unroll
        for (int t = 0; t < TT; ++t)
            h2v[((size_t)t*BB+b)*256 + f] = lif_step(v, z[t] + fb2[f]);
    }
}

__global__ __launch_bounds__(64) void k_fc3(const float* __restrict__ h2v, const float* __restrict__ fw3,
        const float* __restrict__ fb3, float* __restrict__ trans) {
    __shared__ float h3s[TT][9];
    int b = blockIdx.x, tid = threadIdx.x;
    if (tid < TT*9) {
        int t = tid/9, oo = tid%9;
        float z = 0.f;
        for (int c = 0; c < 256; ++c) z += fw3[oo*256+c]*h2v[((size_t)t*BB+b)*256 + c];
        h3s[t][oo] = z + fb3[oo];
    }
    __syncthreads();
    if (tid < 9) {
        float m = ((h3s[0][tid]+h3s[1][tid]) + (h3s[2][tid]+h3s[3][tid])) * 0.25f;
        int c = tid/3, dd = tid%3;
        trans[b*9+tid] = m + ((c==dd)?1.0f:0.0f);
    }
}

// apply transform; also emit packed float4 (x,y,z,sq) for KNN
__global__ __launch_bounds__(256) void k_trans(const float* __restrict__ x, const float* __restrict__ tr,
        float* __restrict__ xa, float4* __restrict__ xa4) {
    int i = blockIdx.x*256 + threadIdx.x;
    int b = i >> 11, n = i & 2047;
    float p0 = x[((size_t)b*14+0)*NN+n];
    float p1 = x[((size_t)b*14+1)*NN+n];
    float p2 = x[((size_t)b*14+2)*NN+n];
    const float* tb = tr + b*9;
    float a0 = (p0*tb[0] + p1*tb[3]) + p2*tb[6];
    float a1 = (p0*tb[1] + p1*tb[4]) + p2*tb[7];
    float a2 = (p0*tb[2] + p1*tb[5]) + p2*tb[8];
    xa[((size_t)b*14+0)*NN+n] = a0;
    xa[((size_t)b*14+1)*NN+n] = a1;
    xa[((size_t)b*14+2)*NN+n] = a2;
    for (int c = 3; c < 14; ++c) xa[((size_t)b*14+c)*NN+n] = x[((size_t)b*14+c)*NN+n];
    float4 p;
    p.x = a0; p.y = a1; p.z = a2;
    p.w = (a0*a0 + a1*a1) + a2*a2;
    xa4[(size_t)b*NN+n] = p;
}

// KNN: one wave per query point
__global__ __launch_bounds__(256) void k_knn(const float4* __restrict__ xa4, int* __restrict__ idx) {
    int wave = threadIdx.x >> 6, lane = threadIdx.x & 63;
    int b = blockIdx.y;
    int n = blockIdx.x*4 + wave;
    const float4* P = xa4 + (size_t)b*NN;
    float4 q = P[n];
    float sn = q.w;
    float vals[32];
    #pragma unroll
    for (int j = 0; j < 32; ++j) {
        float4 p = P[j*64 + lane];
        float inner = (q.x*p.x + q.y*p.y) + q.z*p.z;
        vals[j] = (2.0f*inner - sn) - p.w;
    }
    for (int k = 0; k < KNB; ++k) {
        float bv = -3.4e38f; int bj = 0;
        #pragma unroll
        for (int j = 0; j < 32; ++j) if (vals[j] > bv) { bv = vals[j]; bj = j; }
        int bm = bj*64 + lane;
        u32 fb = __float_as_uint(bv);
        fb = (fb & 0x80000000u) ? ~fb : (fb | 0x80000000u);
        u64 key = ((u64)fb << 32) | (u32)(~bm);
        #pragma unroll
        for (int o2 = 1; o2 < 64; o2 <<= 1) {
            u64 other = __shfl_xor(key, o2, 64);
            key = (other > key) ? other : key;
        }
        int wm = (int)(~(u32)key);
        if (lane == 0) idx[((size_t)b*NN + n)*KNB + k] = wm;
        int wl = wm & 63, wj = wm >> 6;
        if (lane == wl) {
            #pragma unroll
            for (int j = 0; j < 32; ++j) if (j == wj) vals[j] = -3.4e38f;
        }
    }
}

// fused graph-feature + edge conv1 GEMM: z once + stats partials (bit-identical z)
__global__ __launch_bounds__(256) void k_zstats(const float* __restrict__ xa, const int* __restrict__ idx,
        const float* __restrict__ w1, float* __restrict__ part1, float* __restrict__ z1) {
    __shared__ float w1s[64*28];
    __shared__ float wsum[4][64], wsq[4][64];
    int pt = blockIdx.x, b = blockIdx.y;
    int p0 = pt*256, tid = threadIdx.x;
    int p = p0 + tid;
    for (int l = tid; l < 64*28; l += 256) w1s[l] = w1[l];
    __syncthreads();
    int n = p >> 4;
    int mm = idx[((size_t)b*NN+n)*KNB + (p & 15)];
    float gr[28];
    #pragma unroll
    for (int c = 0; c < 14; ++c) {
        float ctr = xa[((size_t)b*14+c)*NN + n];
        float nb  = xa[((size_t)b*14+c)*NN + mm];
        gr[c] = ctr;
        gr[14+c] = nb - ctr;
    }
    int wv = tid>>6, lane = tid&63;
    for (int d = 0; d < 64; ++d) {
        float z = 0.f;
        #pragma unroll
        for (int c = 0; c < 28; ++c) z += w1s[d*28+c]*gr[c];
        z1[((size_t)b*64+d)*PP + p] = z;
        float s = z, q = z*z;
        #pragma unroll
        for (int o = 1; o < 64; o <<= 1) { s += __shfl_xor(s, o, 64); q += __shfl_xor(q, o, 64); }
        if (lane == 0) { wsum[wv][d] = s; wsq[wv][d] = q; }
    }
    __syncthreads();
    if (tid < 64) {
        float s = (wsum[0][tid]+wsum[1][tid])+(wsum[2][tid]+wsum[3][tid]);
        float q = (wsq[0][tid]+wsq[1][tid])+(wsq[2][tid]+wsq[3][tid]);
        size_t blk = (size_t)b*128 + pt;
        part1[(blk*64 + tid)*2+0] = s;
        part1[(blk*64 + tid)*2+1] = q;
    }
}

__global__ __launch_bounds__(256) void k_reduce(const float* __restrict__ part, float* __restrict__ stats, int nch, int nblk, double M) {
    __shared__ double sred[256], qred[256];
    int ch = blockIdx.x, tid = threadIdx.x;
    double s = 0.0, q = 0.0;
    for (int i = tid; i < nblk; i += 256) {
        s += (double)part[((size_t)i*nch + ch)*2 + 0];
        q += (double)part[((size_t)i*nch + ch)*2 + 1];
    }
    sred[tid] = s; qred[tid] = q;
    __syncthreads();
    for (int off = 128; off > 0; off >>= 1) {
        if (tid < off) { sred[tid] += sred[tid+off]; qred[tid] += qred[tid+off]; }
        __syncthreads();
    }
    if (tid == 0) {
        double mu = sred[0] / M;
        double var = qred[0] / M - mu*mu;
        if (var < 0.0) var = 0.0;
        stats[ch*2+0] = (float)mu;
        stats[ch*2+1] = 1.0f / sqrtf((float)var + EPSB);
    }
}

// edge conv1 apply from stored z1
__global__ __launch_bounds__(256) void k_h1(const float* __restrict__ z1,
        const float* __restrict__ st1, const float* __restrict__ g1, const float* __restrict__ be1,
        u64* __restrict__ h1b, u64* __restrict__ h1n) {
    int tid = threadIdx.x;
    int b = blockIdx.y;
    int p0 = blockIdx.x*256;
    int p = p0 + tid;
    int wordbase = (p0>>6) + (tid>>6);
    u64 pm[TT] = {0,0,0,0};
    for (int d = 0; d < 64; ++d) {
        float z = z1[((size_t)b*64+d)*PP + p];
        float mu = st1[d*2+0], iv = st1[d*2+1];
        float v = 0.f;
        #pragma unroll
        for (int t = 0; t < TT; ++t) {
            float y = (z - mu) * iv * g1[t*64+d] + be1[t*64+d];
            float s = lif_step(v, y);
            u64 m = __ballot(s != 0.f);
            if ((tid & 63) == 0) h1b[((size_t)(t*BB+b)*64 + d)*512 + wordbase] = m;
            pm[t] |= ((u64)(s != 0.f)) << d;
        }
    }
    #pragma unroll
    for (int t = 0; t < TT; ++t) h1n[(size_t)(t*BB+b)*PP + p] = pm[t];
}

// ---------------- Tiled popcount Grams (exact int counts) ----------------
__global__ __launch_bounds__(256) void k_gram_h1(const u64* __restrict__ h1b, int* __restrict__ Mi) {
    __shared__ u64 tw[64*65];
    int tid = threadIdx.x;
    int w0 = blockIdx.x*64;
    int tb = blockIdx.y;
    int t = tb >> 3;
    const u64* src = h1b + (size_t)tb*64*512;
    for (int l = tid; l < 64*64; l += 256) {
        int c = l >> 6, w = l & 63;
        tw[c*65+w] = src[(size_t)c*512 + w0 + w];
    }
    __syncthreads();
    int q = tid >> 4, r = tid & 15;
    int acc[4][4];
    #pragma unroll
    for (int i=0;i<4;++i)
        #pragma unroll
        for (int j=0;j<4;++j) acc[i][j]=0;
    #pragma unroll 4
    for (int w = 0; w < 64; ++w) {
        u64 av[4], bv[4];
        #pragma unroll
        for (int i=0;i<4;++i) av[i] = tw[(q+16*i)*65+w];
        #pragma unroll
        for (int j=0;j<4;++j) bv[j] = tw[(r+16*j)*65+w];
        #pragma unroll
        for (int i=0;i<4;++i)
            #pragma unroll
            for (int j=0;j<4;++j) acc[i][j] += (int)__popcll(av[i]&bv[j]);
    }
    #pragma unroll
    for (int i=0;i<4;++i)
        #pragma unroll
        for (int j=0;j<4;++j)
            atomicAdd(&Mi[((size_t)t*64 + q+16*i)*64 + r+16*j], acc[i][j]);
}

template<int C>
__global__ __launch_bounds__(256) void k_gram2(const u64* __restrict__ bits, int* __restrict__ Mi) {
    __shared__ u64 ta[64*33], tbt[64*33];
    int tid = threadIdx.x;
    int ci0 = blockIdx.x*64, cj0 = blockIdx.y*64;
    int tb = blockIdx.z;
    int t = tb >> 3;
    const u64* srcA = bits + ((size_t)tb*C + ci0)*32;
    const u64* srcB = bits + ((size_t)tb*C + cj0)*32;
    for (int l = tid; l < 64*32; l += 256) {
        int rr = l >> 5, w = l & 31;
        ta[rr*33+w]  = srcA[(size_t)rr*32+w];
        tbt[rr*33+w] = srcB[(size_t)rr*32+w];
    }
    __syncthreads();
    int q = tid >> 4, r = tid & 15;
    int acc[4][4];
    #pragma unroll
    for (int i=0;i<4;++i)
        #pragma unroll
        for (int j=0;j<4;++j) acc[i][j]=0;
    #pragma unroll 4
    for (int w = 0; w < 32; ++w) {
        u64 av[4], bv[4];
        #pragma unroll
        for (int i=0;i<4;++i) av[i] = ta[(q+16*i)*33+w];
        #pragma unroll
        for (int j=0;j<4;++j) bv[j] = tbt[(r+16*j)*33+w];
        #pragma unroll
        for (int i=0;i<4;++i)
            #pragma unroll
            for (int j=0;j<4;++j) acc[i][j] += (int)__popcll(av[i]&bv[j]);
    }
    #pragma unroll
    for (int i=0;i<4;++i)
        #pragma unroll
        for (int j=0;j<4;++j)
            atomicAdd(&Mi[((size_t)t*C + ci0+q+16*i)*C + cj0+r+16*j], acc[i][j]);
}

// project int Gram through weights -> per-(t,ch) (mean, inv_std)
template<int CIN>
__global__ void k_proj(const int* __restrict__ Mf, const float* __restrict__ w,
        float* __restrict__ st, int COUT, double cnt) {
    __shared__ double z2s[256], mns[256];
    int ch = blockIdx.x, t = blockIdx.y, c2 = threadIdx.x;
    const int* Mt = Mf + (size_t)t*CIN*CIN;
    double y = 0.0;
    for (int c = 0; c < CIN; ++c)
        y += (double)w[(size_t)ch*CIN+c] * (double)Mt[(size_t)c*CIN + c2];
    double wc2 = (double)w[(size_t)ch*CIN+c2];
    z2s[c2] = wc2 * y;
    mns[c2] = wc2 * (double)Mt[(size_t)c2*CIN + c2];
    __syncthreads();
    for (int off = CIN>>1; off > 0; off >>= 1) {
        if (c2 < off) { z2s[c2] += z2s[c2+off]; mns[c2] += mns[c2+off]; }
        __syncthreads();
    }
    if (c2 == 0) {
        double mu = mns[0] / cnt;
        double var = z2s[0] / cnt - mu*mu;
        if (var < 0.0) var = 0.0;
        st[((size_t)t*COUT+ch)*2+0] = (float)mu;
        st[((size_t)t*COUT+ch)*2+1] = 1.0f / sqrtf((float)var + EPSB);
    }
}

// weight prep: fp32 w[F][K] -> exact 3-way bf16 split in MFMA-frag layout [K/8][F][8]
__global__ __launch_bounds__(256) void k_wprep(const float* __restrict__ w,
        short* __restrict__ hi, short* __restrict__ mid, short* __restrict__ lo, int F, int K) {
    int i = blockIdx.x*256 + threadIdx.x;
    if (i >= F*K) return;
    int f = i / K, k = i % K;
    float wv = w[i];
    u32 b0 = __float_as_uint(wv);
    float h = __uint_as_float(b0 & 0xFFFF0000u);
    float r1 = wv - h;
    u32 b1 = __float_as_uint(r1);
    float m = __uint_as_float(b1 & 0xFFFF0000u);
    float r2 = r1 - m;
    u32 b2 = __float_as_uint(r2);
    size_t o = ((size_t)(k>>3)*F + f)*8 + (k&7);
    hi[o]  = (short)(b0 >> 16);
    mid[o] = (short)(b1 >> 16);
    lo[o]  = (short)(b2 >> 16);
}

// ---------------- MFMA spike conv (KT=64 LDS weight tiles + LUT A-expansion) ----------------
template<int K, int F, int MODE, bool BITS>
__global__ __launch_bounds__(256) void k_mconv(
        const void* __restrict__ Asrc,
        const short* __restrict__ Whi, const short* __restrict__ Wmd, const short* __restrict__ Wlo,
        const float* __restrict__ st, const float* __restrict__ ga, const float* __restrict__ be,
        const float* __restrict__ bias,
        u16* __restrict__ outp, u32* __restrict__ outm, int NPTS) {
    constexpr int KT = 64;
    constexpr int ROWS = (KT/8)*3;
    constexpr int NW = (K+63)/64;
    __shared__ short wsm[ROWS*512];
    __shared__ short sptab[BITS ? 256*8 : 8];
    __shared__ u32 morr[TT][64];
    int tid = threadIdx.x;
    int wave = tid >> 6, lane = tid & 63;
    int l15 = lane & 15, lg = lane >> 4;
    int b = blockIdx.z;
    int n_base = blockIdx.x*64 + wave*16;
    int f0 = blockIdx.y*64;
    if (MODE == 0 || MODE == 2)
        for (int l = tid; l < TT*64; l += 256) morr[l>>6][l&63] = 0u;
    if (BITS) {
        #pragma unroll
        for (int j = 0; j < 8; ++j) sptab[tid*8+j] = (short)(((tid>>j)&1) * 0x3F80);
    }

    f4 acc[4][TT];
    #pragma unroll
    for (int i = 0; i < 4; ++i)
        #pragma unroll
        for (int t = 0; t < TT; ++t) acc[i][t] = (f4)0.f;

    u64 aw[TT][NW];
    const u16* Au[TT];
    #pragma unroll
    for (int t = 0; t < TT; ++t) {
        if (BITS) {
            const u64* Ab = (const u64*)Asrc + ((size_t)(t*BB+b)*NPTS + n_base + l15)*NW;
            #pragma unroll
            for (int wq = 0; wq < NW; ++wq) aw[t][wq] = Ab[wq];
        } else {
            Au[t] = (const u16*)Asrc + ((size_t)(t*BB+b)*NPTS + n_base + l15)*K + lg*8;
        }
    }
    const short* Wsrc[3] = {Whi, Wmd, Wlo};

    #pragma unroll
    for (int kt = 0; kt < K; kt += KT) {
        if (kt > 0) __syncthreads();
        #pragma unroll
        for (int r = wave; r < ROWS; r += 4) {
            int kq = r/3, s = r - kq*3;
            const short* g = Wsrc[s] + ((size_t)((kt>>3) + kq)*F + f0)*8 + lane*8;
            GLOAD_LDS16(g, &wsm[r*512]);
        }
        __syncthreads();
        #pragma unroll
        for (int k0 = 0; k0 < KT; k0 += 32) {
            int kg = kt + k0;
            short8 a[TT];
            #pragma unroll
            for (int t = 0; t < TT; ++t) {
                if (BITS) {
                    u32 byte = (u32)(aw[t][kg>>6] >> ((kg&63) + lg*8)) & 0xFFu;
                    a[t] = *(const short8*)(sptab + byte*8);
                } else {
                    a[t] = *(const short8*)(Au[t] + kg);
                }
            }
            int kql = (k0>>3) + lg;
            #pragma unroll
            for (int fs = 0; fs < 4; ++fs) {
                const short* base = wsm + kql*1536 + (fs*16+l15)*8;
                short8 whi = *(const short8*)(base);
                short8 wmd = *(const short8*)(base + 512);
                short8 wlo = *(const short8*)(base + 1024);
                #pragma unroll
                for (int t = 0; t < TT; ++t) {
                    acc[fs][t] = __builtin_amdgcn_mfma_f32_16x16x32_bf16(a[t], whi, acc[fs][t], 0, 0, 0);
                    acc[fs][t] = __builtin_amdgcn_mfma_f32_16x16x32_bf16(a[t], wmd, acc[fs][t], 0, 0, 0);
                    acc[fs][t] = __builtin_amdgcn_mfma_f32_16x16x32_bf16(a[t], wlo, acc[fs][t], 0, 0, 0);
                }
            }
        }
    }
    if (MODE == 1) {
        #pragma unroll
        for (int fs = 0; fs < 4; ++fs) {
            int f = f0 + fs*16 + l15;
            #pragma unroll
            for (int reg = 0; reg < 4; ++reg) {
                int n = n_base + lg*4 + reg;
                float v = 0.f;
                #pragma unroll
                for (int t = 0; t < TT; ++t) {
                    int ch = t*F + f;
                    float y = (acc[fs][t][reg] - st[(size_t)ch*2+0])*st[(size_t)ch*2+1]*ga[ch] + be[ch];
                    float s = lif_step(v, y);
                    outp[((size_t)(t*BB+b)*NPTS + n)*F + f] = (s != 0.f) ? (u16)0x3F80 : (u16)0;
                }
            }
        }
    } else if (MODE == 3) {
        #pragma unroll
        for (int fs = 0; fs < 4; ++fs) {
            int f = f0 + fs*16 + l15;
            u32 nib = 0u;
            #pragma unroll
            for (int reg = 0; reg < 4; ++reg) {
                float v = 0.f;
                #pragma unroll
                for (int t = 0; t < TT; ++t) {
                    int ch = t*F + f;
                    float y = (acc[fs][t][reg] - st[(size_t)ch*2+0])*st[(size_t)ch*2+1]*ga[ch] + be[ch];
                    float s = lif_step(v, y);
                    if (s != 0.f) nib |= (1u << t);
                }
            }
            nib |= __shfl_xor(nib, 16, 64);
            nib |= __shfl_xor(nib, 32, 64);
            if (lg == 0) {
                int n_pt = n_base >> 4;
                #pragma unroll
                for (int t = 0; t < TT; ++t)
                    outp[((size_t)(t*BB+b)*(NPTS>>4) + n_pt)*F + f] = ((nib>>t)&1u) ? (u16)0x3F80 : (u16)0;
            }
        }
    } else {
        #pragma unroll
        for (int fs = 0; fs < 4; ++fs) {
            int f = f0 + fs*16 + l15;
            u32 any[TT] = {0,0,0,0};
            float bb = (MODE == 0) ? bias[f] : 0.f;
            #pragma unroll
            for (int reg = 0; reg < 4; ++reg) {
                float v = 0.f;
                #pragma unroll
                for (int t = 0; t < TT; ++t) {
                    float y;
                    if (MODE == 0) y = acc[fs][t][reg] + bb;
                    else {
                        int ch = t*F + f;
                        y = (acc[fs][t][reg] - st[(size_t)ch*2+0])*st[(size_t)ch*2+1]*ga[ch] + be[ch];
                    }
                    float s = lif_step(v, y);
                    if (s != 0.f) any[t] = 1u;
                }
            }
            #pragma unroll
            for (int t = 0; t < TT; ++t) if (any[t]) atomicOr(&morr[t][fs*16+l15], 1u);
        }
        __syncthreads();
        for (int l = tid; l < TT*64; l += 256)
            if (morr[l>>6][l&63]) atomicOr(&outm[((size_t)((l>>6)*BB+b))*F + f0 + (l&63)], 1u);
    }
}

// ---------------- conv4 specialized: same math/order as k_mconv<256,1024,2,false>, reg-capped ----------------
// __launch_bounds__(256,4) caps the unified reg budget at 128 (64 acc + <=64 VGPR) -> 4 waves/SIMD.
__global__ __launch_bounds__(256, 4) void k_conv4(
        const u16* __restrict__ Asrc,
        const short* __restrict__ Whi, const short* __restrict__ Wmd, const short* __restrict__ Wlo,
        const float* __restrict__ st, const float* __restrict__ ga, const float* __restrict__ be,
        u32* __restrict__ outm) {
    constexpr int K = 256, F = 1024;
    __shared__ short wsm[24*512];
    __shared__ u32 morr[TT][64];
    int tid = threadIdx.x;
    int wave = tid >> 6, lane = tid & 63;
    int l15 = lane & 15, lg = lane >> 4;
    int b = blockIdx.z;
    int n_base = blockIdx.x*64 + wave*16;
    int f0 = blockIdx.y*64;
    for (int l = tid; l < TT*64; l += 256) morr[l>>6][l&63] = 0u;

    f4 acc[4][TT];
    #pragma unroll
    for (int i = 0; i < 4; ++i)
        #pragma unroll
        for (int t = 0; t < TT; ++t) acc[i][t] = (f4)0.f;

    const u16* Au = Asrc + ((size_t)b*NN + n_base + l15)*K + lg*8;
    constexpr size_t TSTR = (size_t)BB*NN*K;   // per-t element stride
    const short* Wsrc[3] = {Whi, Wmd, Wlo};

    #pragma unroll
    for (int kt = 0; kt < K; kt += 64) {
        if (kt > 0) __syncthreads();
        #pragma unroll
        for (int r = wave; r < 24; r += 4) {
            int kq = r/3, s = r - kq*3;
            const short* g = Wsrc[s] + ((size_t)((kt>>3) + kq)*F + f0)*8 + lane*8;
            GLOAD_LDS16(g, &wsm[r*512]);
        }
        __syncthreads();
        #pragma unroll
        for (int k0 = 0; k0 < 64; k0 += 32) {
            int kg = kt + k0;
            short8 a[TT];
            #pragma unroll
            for (int t = 0; t < TT; ++t)
                a[t] = *(const short8*)(Au + (size_t)t*TSTR + kg);
            int kql = (k0>>3) + lg;
            #pragma unroll
            for (int fs = 0; fs < 4; ++fs) {
                const short* base = wsm + kql*1536 + (fs*16+l15)*8;
                short8 whi = *(const short8*)(base);
                short8 wmd = *(const short8*)(base + 512);
                short8 wlo = *(const short8*)(base + 1024);
                #pragma unroll
                for (int t = 0; t < TT; ++t) {
                    acc[fs][t] = __builtin_amdgcn_mfma_f32_16x16x32_bf16(a[t], whi, acc[fs][t], 0, 0, 0);
                    acc[fs][t] = __builtin_amdgcn_mfma_f32_16x16x32_bf16(a[t], wmd, acc[fs][t], 0, 0, 0);
                    acc[fs][t] = __builtin_amdgcn_mfma_f32_16x16x32_bf16(a[t], wlo, acc[fs][t], 0, 0, 0);
                }
            }
        }
    }
    #pragma unroll
    for (int fs = 0; fs < 4; ++fs) {
        int f = f0 + fs*16 + l15;
        u32 any[TT] = {0,0,0,0};
        #pragma unroll
        for (int reg = 0; reg < 4; ++reg) {
            float v = 0.f;
            #pragma unroll
            for (int t = 0; t < TT; ++t) {
                int ch = t*F + f;
                float y = (acc[fs][t][reg] - st[(size_t)ch*2+0])*st[(size_t)ch*2+1]*ga[ch] + be[ch];
                float s = lif_step(v, y);
                if (s != 0.f) any[t] = 1u;
            }
        }
        #pragma unroll
        for (int t = 0; t < TT; ++t) if (any[t]) atomicOr(&morr[t][fs*16+l15], 1u);
    }
    __syncthreads();
    for (int l = tid; l < TT*64; l += 256)
        if (morr[l>>6][l&63]) atomicOr(&outm[((size_t)((l>>6)*BB+b))*F + f0 + (l&63)], 1u);
}

// repack point-major bf16-u16 spikes [t][b][n][C] -> channel-major bits [t][b][C][32 words over n]
template<int C>
__global__ __launch_bounds__(256) void k_repack(const u16* __restrict__ sp, u64* __restrict__ bits) {
    __shared__ u16 tile[64][C+2];
    int tid = threadIdx.x;
    int nw = blockIdx.x, b = blockIdx.y, t = blockIdx.z;
    const u16* src = sp + ((size_t)(t*BB+b)*NN + nw*64)*C;
    for (int i = tid*2; i < 64*C; i += 512) {
        u32 v = *(const u32*)(src + i);
        int r = i / C, c = i % C;
        *(u32*)&tile[r][c] = v;
    }
    __syncthreads();
    int wave = tid >> 6, lane = tid & 63;
    for (int c = wave; c < C; c += 4) {
        u64 m = __ballot(tile[lane][c] != 0);
        if (lane == 0) bits[((size_t)(t*BB+b)*C + c)*32 + nw] = m;
    }
}

__global__ __launch_bounds__(256) void k_out(const u32* __restrict__ mx4, float* __restrict__ out) {
    int i = blockIdx.x*256 + threadIdx.x;
    int b = i >> 10, g = i & 1023;
    float s = (float)(mx4[((size_t)0*BB+b)*1024+g] + mx4[((size_t)1*BB+b)*1024+g]
                    + mx4[((size_t)2*BB+b)*1024+g] + mx4[((size_t)3*BB+b)*1024+g]);
    out[i] = s * 0.25f;
}

extern "C" void kernel_launch(void* const* d_in, const int* in_sizes, int n_in,
                              void* d_out, int out_size, void* d_ws, size_t ws_size,
                              hipStream_t stream) {
    (void)in_sizes; (void)n_in; (void)out_size;
    const float* x    = (const float*)d_in[0];
    const float* tw1  = (const float*)d_in[1];
    const float* tb1  = (const float*)d_in[2];
    const float* tw2  = (const float*)d_in[3];
    const float* tb2  = (const float*)d_in[4];
    const float* tw3  = (const float*)d_in[5];
    const float* tb3  = (const float*)d_in[6];
    const float* tfw1 = (const float*)d_in[7];
    const float* tfb1 = (const float*)d_in[8];
    const float* tfw2 = (const float*)d_in[9];
    const float* tfb2 = (const float*)d_in[10];
    const float* tfw3 = (const float*)d_in[11];
    const float* tfb3 = (const float*)d_in[12];
    const float* w1   = (const float*)d_in[13];
    const float* w2   = (const float*)d_in[14];
    const float* w3   = (const float*)d_in[15];
    const float* w4   = (const float*)d_in[16];
    const float* g1   = (const float*)d_in[17];
    const float* be1  = (const float*)d_in[18];
    const float* g2   = (const float*)d_in[19];
    const float* be2  = (const float*)d_in[20];
    const float* g3   = (const float*)d_in[21];
    const float* be3  = (const float*)d_in[22];
    const float* g4   = (const float*)d_in[23];
    const float* be4  = (const float*)d_in[24];

    char* wsb = (char*)d_ws;
    size_t off = 0;
    auto alloc = [&](size_t bytes) -> void* {
        void* p = wsb + off;
        off = (off + bytes + 255) & ~(size_t)255;
        return p;
    };
    u64* s1b   = (u64*)alloc(sizeof(u64)*(size_t)TT*BB*NN);
    u64* s2b   = (u64*)alloc(sizeof(u64)*(size_t)TT*BB*NN*2);
    u32* mx    = (u32*)alloc(sizeof(u32)*(size_t)TT*BB*1024);
    u32* mx4   = (u32*)alloc(sizeof(u32)*(size_t)TT*BB*1024);
    float* trs = (float*)alloc(sizeof(float)*BB*9);
    float* xa  = (float*)alloc(sizeof(float)*(size_t)BB*14*NN);
    float4* xa4 = (float4*)alloc(sizeof(float4)*(size_t)BB*NN);
    int* idx   = (int*)alloc(sizeof(int)*(size_t)BB*NN*KNB);
    float* z1  = (float*)alloc(sizeof(float)*(size_t)BB*64*PP);
    float* part1 = (float*)alloc(sizeof(float)*(size_t)1024*64*2);
    float* st1 = (float*)alloc(sizeof(float)*64*2);
    float* st2 = (float*)alloc(sizeof(float)*512*2);
    float* st3 = (float*)alloc(sizeof(float)*1024*2);
    float* st4 = (float*)alloc(sizeof(float)*4096*2);
    float* h1v = (float*)alloc(sizeof(float)*(size_t)TT*BB*512);
    float* h2v = (float*)alloc(sizeof(float)*(size_t)TT*BB*256);
    u64* h1b = (u64*)alloc(sizeof(u64)*(size_t)TT*BB*64*512);
    u64* h1n = (u64*)alloc(sizeof(u64)*(size_t)TT*BB*PP);
    u16* m2p = (u16*)alloc(sizeof(u16)*(size_t)TT*BB*NN*128);
    u16* h3p = (u16*)alloc(sizeof(u16)*(size_t)TT*BB*NN*256);
    u64* m2b = (u64*)alloc(sizeof(u64)*(size_t)TT*BB*128*32);
    u64* h3b = (u64*)alloc(sizeof(u64)*(size_t)TT*BB*256*32);
    int* Mi64  = (int*)alloc(sizeof(int)*(size_t)TT*64*64);
    int* Mi128 = (int*)alloc(sizeof(int)*(size_t)TT*128*128);
    int* Mi256 = (int*)alloc(sizeof(int)*(size_t)TT*256*256);
    short* wp2h = (short*)alloc(sizeof(short)*(size_t)128*64);
    short* wp2m = (short*)alloc(sizeof(short)*(size_t)128*64);
    short* wp2l = (short*)alloc(sizeof(short)*(size_t)128*64);
    short* wp3h = (short*)alloc(sizeof(short)*(size_t)256*128);
    short* wp3m = (short*)alloc(sizeof(short)*(size_t)256*128);
    short* wp3l = (short*)alloc(sizeof(short)*(size_t)256*128);
    short* wp4h = (short*)alloc(sizeof(short)*(size_t)1024*256);
    short* wp4m = (short*)alloc(sizeof(short)*(size_t)1024*256);
    short* wp4l = (short*)alloc(sizeof(short)*(size_t)1024*256);
    short* wpth = (short*)alloc(sizeof(short)*(size_t)1024*128);
    short* wptm = (short*)alloc(sizeof(short)*(size_t)1024*128);
    short* wptl = (short*)alloc(sizeof(short)*(size_t)1024*128);
    if (off > ws_size) return;

    hipMemsetAsync(mx, 0, sizeof(u32)*(size_t)TT*BB*1024, stream);
    hipMemsetAsync(mx4, 0, sizeof(u32)*(size_t)TT*BB*1024, stream);
    hipMemsetAsync(Mi64, 0, sizeof(int)*(size_t)TT*64*64, stream);
    hipMemsetAsync(Mi128, 0, sizeof(int)*(size_t)TT*128*128, stream);
    hipMemsetAsync(Mi256, 0, sizeof(int)*(size_t)TT*256*256, stream);

    // weight prep (exact 3-way bf16 split)
    k_wprep<<<dim3((128*64+255)/256), dim3(256), 0, stream>>>(w2, wp2h, wp2m, wp2l, 128, 64);
    k_wprep<<<dim3((256*128+255)/256), dim3(256), 0, stream>>>(w3, wp3h, wp3m, wp3l, 256, 128);
    k_wprep<<<dim3((1024*256+255)/256), dim3(256), 0, stream>>>(w4, wp4h, wp4m, wp4l, 1024, 256);
    k_wprep<<<dim3((1024*128+255)/256), dim3(256), 0, stream>>>(tw3, wpth, wptm, wptl, 1024, 128);

    // T-Net
    k_tnet1<<<dim3(64), dim3(256), 0, stream>>>(x, tw1, tb1, s1b);
    k_tnet2<<<dim3(64, 4), dim3(256), 0, stream>>>(s1b, tw2, tb2, (u32*)s2b);
    k_mconv<128,1024,0,true><<<dim3(32,16,8), dim3(256), 0, stream>>>(
        s2b, wpth, wptm, wptl, nullptr, nullptr, nullptr, tb3, nullptr, mx, NN);
    k_fc1<<<dim3(512, 8), dim3(64), 0, stream>>>(mx, tfw1, tfb1, h1v);
    k_fc2<<<dim3(256, 8), dim3(64), 0, stream>>>(h1v, tfw2, tfb2, h2v);
    k_fc3<<<dim3(8), dim3(64), 0, stream>>>(h2v, tfw3, tfb3, trs);
    k_trans<<<dim3(64), dim3(256), 0, stream>>>(x, trs, xa, xa4);
    // KNN (wave-per-query)
    k_knn<<<dim3(NN/4, BB), dim3(256), 0, stream>>>(xa4, idx);
    // fused graph-feature + edge conv1 GEMM (z once) + stats partials
    k_zstats<<<dim3(128, 8), dim3(256), 0, stream>>>(xa, idx, w1, part1, z1);
    k_reduce<<<dim3(64), dim3(256), 0, stream>>>(part1, st1, 64, 1024, 262144.0);
    k_h1<<<dim3(128, 8), dim3(256), 0, stream>>>(z1, st1, g1, be1, h1b, h1n);
    // edge conv2: stats via tiled Gram, apply via MFMA (+ max over k)
    k_gram_h1<<<dim3(8, TT*BB), dim3(256), 0, stream>>>(h1b, Mi64);
    k_proj<64><<<dim3(128, TT), dim3(64), 0, stream>>>(Mi64, w2, st2, 128, 262144.0);
    k_mconv<64,128,3,true><<<dim3(PP/64,2,8), dim3(256), 0, stream>>>(
        h1n, wp2h, wp2m, wp2l, st2, g2, be2, nullptr, m2p, nullptr, PP);
    k_repack<128><<<dim3(32,8,4), dim3(256), 0, stream>>>(m2p, m2b);
    // conv3
    k_gram2<128><<<dim3(2,2,TT*BB), dim3(256), 0, stream>>>(m2b, Mi128);
    k_proj<128><<<dim3(256, TT), dim3(128), 0, stream>>>(Mi128, w3, st3, 256, 16384.0);
    k_mconv<128,256,1,false><<<dim3(32,4,8), dim3(256), 0, stream>>>(
        m2p, wp3h, wp3m, wp3l, st3, g3, be3, nullptr, h3p, nullptr, NN);
    k_repack<256><<<dim3(32,8,4), dim3(256), 0, stream>>>(h3p, h3b);
    // conv4 (reg-capped specialized kernel, bit-identical math)
    k_gram2<256><<<dim3(4,4,TT*BB), dim3(256), 0, stream>>>(h3b, Mi256);
    k_proj<256><<<dim3(1024, TT), dim3(256), 0, stream>>>(Mi256, w4, st4, 1024, 16384.0);
    k_conv4<<<dim3(32,16,8), dim3(256), 0, stream>>>(
        h3p, wp4h, wp4m, wp4l, st4, g4, be4, mx4);
    // output
    k_out<<<dim3(32), dim3(256), 0, stream>>>(mx4, (float*)d_out);
}

// Round 12
// 717.652 us; speedup vs baseline: 1.1230x; 1.0632x over previous
//
#include <hip/hip_runtime.h>
#include <stdint.h>

#define TT 4
#define BB 8
#define NN 2048
#define KNB 16
#define PP (NN*KNB)
#define VTH 1.0f
#define EPSB 1e-5f

typedef unsigned long long u64;
typedef unsigned int u32;
typedef unsigned short u16;
typedef unsigned char u8;
typedef __attribute__((ext_vector_type(8))) short short8;
typedef __attribute__((ext_vector_type(4))) float f4;

#define GLOAD_LDS16(g, l) __builtin_amdgcn_global_load_lds( \
    (const __attribute__((address_space(1))) u32*)(g), \
    (__attribute__((address_space(3))) u32*)(l), 16, 0, 0)

__device__ __forceinline__ float lif_step(float& v, float x) {
    v = v + (x - v) / 2.0f;
    float s = (v - VTH >= 0.0f) ? 1.0f : 0.0f;
    v = v * (1.0f - s);
    return s;
}

// ---------------- T-Net ----------------
__global__ __launch_bounds__(256) void k_tnet1(const float* __restrict__ x, const float* __restrict__ w,
        const float* __restrict__ bi, u64* __restrict__ s1b) {
    int i = blockIdx.x*256 + threadIdx.x;
    int b = i >> 11, n = i & 2047;
    float p0 = x[((size_t)b*14+0)*NN+n];
    float p1 = x[((size_t)b*14+1)*NN+n];
    float p2 = x[((size_t)b*14+2)*NN+n];
    u64 m[TT] = {0,0,0,0};
    for (int d = 0; d < 64; ++d) {
        float z = ((w[d*3+0]*p0 + w[d*3+1]*p1) + w[d*3+2]*p2) + bi[d];
        float v = 0.f;
        #pragma unroll
        for (int t = 0; t < TT; ++t) {
            float s = lif_step(v, z);
            if (s != 0.f) m[t] |= (1ull << d);
        }
    }
    #pragma unroll
    for (int t = 0; t < TT; ++t) s1b[((size_t)t*BB + b)*NN + n] = m[t];
}

// conv2: 64->128, split over 4 channel-chunks of 32 for occupancy
__global__ __launch_bounds__(256) void k_tnet2(const u64* __restrict__ s1b, const float* __restrict__ w,
        const float* __restrict__ bi, u32* __restrict__ s2b32) {
    __shared__ float ws[32*64];
    int tid = threadIdx.x;
    int ec = blockIdx.y;
    for (int l = tid; l < 32*64; l += 256) ws[l] = w[ec*32*64 + l];
    __syncthreads();
    int i = blockIdx.x*256 + tid;
    int b = i >> 11, n = i & 2047;
    u64 m[TT];
    #pragma unroll
    for (int t = 0; t < TT; ++t) m[t] = s1b[((size_t)t*BB+b)*NN+n];
    u32 o[TT] = {0,0,0,0};
    for (int el = 0; el < 32; ++el) {
        float z[TT] = {0.f,0.f,0.f,0.f};
        #pragma unroll 8
        for (int d = 0; d < 64; ++d) {
            float wv = ws[el*64+d];
            #pragma unroll
            for (int t = 0; t < TT; ++t) z[t] += ((m[t]>>d)&1ull) ? wv : 0.f;
        }
        float v = 0.f, bb = bi[ec*32 + el];
        #pragma unroll
        for (int t = 0; t < TT; ++t) {
            float s = lif_step(v, z[t] + bb);
            if (s != 0.f) o[t] |= (1u << el);
        }
    }
    #pragma unroll
    for (int t = 0; t < TT; ++t)
        s2b32[(((size_t)t*BB+b)*NN+n)*4 + ec] = o[t];
}

// FC head, wave-parallel
__global__ __launch_bounds__(64) void k_fc1(const u32* __restrict__ mx, const float* __restrict__ fw1,
        const float* __restrict__ fb1, float* __restrict__ h1v) {
    int f = blockIdx.x, b = blockIdx.y, lane = threadIdx.x;
    float wr[16];
    #pragma unroll
    for (int j = 0; j < 16; ++j) wr[j] = fw1[(size_t)f*1024 + j*64 + lane];
    float z[TT];
    #pragma unroll
    for (int t = 0; t < TT; ++t) {
        float s = 0.f;
        #pragma unroll
        for (int j = 0; j < 16; ++j)
            s += wr[j] * (float)mx[((size_t)t*BB+b)*1024 + j*64 + lane];
        #pragma unroll
        for (int o = 1; o < 64; o <<= 1) s += __shfl_xor(s, o, 64);
        z[t] = s;
    }
    if (lane == 0) {
        float v = 0.f;
        #pragma unroll
        for (int t = 0; t < TT; ++t)
            h1v[((size_t)t*BB+b)*512 + f] = lif_step(v, z[t] + fb1[f]);
    }
}

__global__ __launch_bounds__(64) void k_fc2(const float* __restrict__ h1v, const float* __restrict__ fw2,
        const float* __restrict__ fb2, float* __restrict__ h2v) {
    int f = blockIdx.x, b = blockIdx.y, lane = threadIdx.x;
    float wr[8];
    #pragma unroll
    for (int j = 0; j < 8; ++j) wr[j] = fw2[(size_t)f*512 + j*64 + lane];
    float z[TT];
    #pragma unroll
    for (int t = 0; t < TT; ++t) {
        float s = 0.f;
        #pragma unroll
        for (int j = 0; j < 8; ++j)
            s += wr[j] * h1v[((size_t)t*BB+b)*512 + j*64 + lane];
        #pragma unroll
        for (int o = 1; o < 64; o <<= 1) s += __shfl_xor(s, o, 64);
        z[t] = s;
    }
    if (lane == 0) {
        float v = 0.f;
        #pragma unroll
        for (int t = 0; t < TT; ++t)
            h2v[((size_t)t*BB+b)*256 + f] = lif_step(v, z[t] + fb2[f]);
    }
}

__global__ __launch_bounds__(64) void k_fc3(const float* __restrict__ h2v, const float* __restrict__ fw3,
        const float* __restrict__ fb3, float* __restrict__ trans) {
    __shared__ float h3s[TT][9];
    int b = blockIdx.x, tid = threadIdx.x;
    if (tid < TT*9) {
        int t = tid/9, oo = tid%9;
        float z = 0.f;
        for (int c = 0; c < 256; ++c) z += fw3[oo*256+c]*h2v[((size_t)t*BB+b)*256 + c];
        h3s[t][oo] = z + fb3[oo];
    }
    __syncthreads();
    if (tid < 9) {
        float m = ((h3s[0][tid]+h3s[1][tid]) + (h3s[2][tid]+h3s[3][tid])) * 0.25f;
        int c = tid/3, dd = tid%3;
        trans[b*9+tid] = m + ((c==dd)?1.0f:0.0f);
    }
}

// apply transform; also emit packed float4 (x,y,z,sq) for KNN
__global__ __launch_bounds__(256) void k_trans(const float* __restrict__ x, const float* __restrict__ tr,
        float* __restrict__ xa, float4* __restrict__ xa4) {
    int i = blockIdx.x*256 + threadIdx.x;
    int b = i >> 11, n = i & 2047;
    float p0 = x[((size_t)b*14+0)*NN+n];
    float p1 = x[((size_t)b*14+1)*NN+n];
    float p2 = x[((size_t)b*14+2)*NN+n];
    const float* tb = tr + b*9;
    float a0 = (p0*tb[0] + p1*tb[3]) + p2*tb[6];
    float a1 = (p0*tb[1] + p1*tb[4]) + p2*tb[7];
    float a2 = (p0*tb[2] + p1*tb[5]) + p2*tb[8];
    xa[((size_t)b*14+0)*NN+n] = a0;
    xa[((size_t)b*14+1)*NN+n] = a1;
    xa[((size_t)b*14+2)*NN+n] = a2;
    for (int c = 3; c < 14; ++c) xa[((size_t)b*14+c)*NN+n] = x[((size_t)b*14+c)*NN+n];
    float4 p;
    p.x = a0; p.y = a1; p.z = a2;
    p.w = (a0*a0 + a1*a1) + a2*a2;
    xa4[(size_t)b*NN+n] = p;
}

// KNN: one wave per query point
__global__ __launch_bounds__(256) void k_knn(const float4* __restrict__ xa4, int* __restrict__ idx) {
    int wave = threadIdx.x >> 6, lane = threadIdx.x & 63;
    int b = blockIdx.y;
    int n = blockIdx.x*4 + wave;
    const float4* P = xa4 + (size_t)b*NN;
    float4 q = P[n];
    float sn = q.w;
    float vals[32];
    #pragma unroll
    for (int j = 0; j < 32; ++j) {
        float4 p = P[j*64 + lane];
        float inner = (q.x*p.x + q.y*p.y) + q.z*p.z;
        vals[j] = (2.0f*inner - sn) - p.w;
    }
    for (int k = 0; k < KNB; ++k) {
        float bv = -3.4e38f; int bj = 0;
        #pragma unroll
        for (int j = 0; j < 32; ++j) if (vals[j] > bv) { bv = vals[j]; bj = j; }
        int bm = bj*64 + lane;
        u32 fb = __float_as_uint(bv);
        fb = (fb & 0x80000000u) ? ~fb : (fb | 0x80000000u);
        u64 key = ((u64)fb << 32) | (u32)(~bm);
        #pragma unroll
        for (int o2 = 1; o2 < 64; o2 <<= 1) {
            u64 other = __shfl_xor(key, o2, 64);
            key = (other > key) ? other : key;
        }
        int wm = (int)(~(u32)key);
        if (lane == 0) idx[((size_t)b*NN + n)*KNB + k] = wm;
        int wl = wm & 63, wj = wm >> 6;
        if (lane == wl) {
            #pragma unroll
            for (int j = 0; j < 32; ++j) if (j == wj) vals[j] = -3.4e38f;
        }
    }
}

// fused graph-feature + edge conv1 GEMM: z once + stats partials (bit-identical z)
__global__ __launch_bounds__(256) void k_zstats(const float* __restrict__ xa, const int* __restrict__ idx,
        const float* __restrict__ w1, float* __restrict__ part1, float* __restrict__ z1) {
    __shared__ float w1s[64*28];
    __shared__ float wsum[4][64], wsq[4][64];
    int pt = blockIdx.x, b = blockIdx.y;
    int p0 = pt*256, tid = threadIdx.x;
    int p = p0 + tid;
    for (int l = tid; l < 64*28; l += 256) w1s[l] = w1[l];
    __syncthreads();
    int n = p >> 4;
    int mm = idx[((size_t)b*NN+n)*KNB + (p & 15)];
    float gr[28];
    #pragma unroll
    for (int c = 0; c < 14; ++c) {
        float ctr = xa[((size_t)b*14+c)*NN + n];
        float nb  = xa[((size_t)b*14+c)*NN + mm];
        gr[c] = ctr;
        gr[14+c] = nb - ctr;
    }
    int wv = tid>>6, lane = tid&63;
    for (int d = 0; d < 64; ++d) {
        float z = 0.f;
        #pragma unroll
        for (int c = 0; c < 28; ++c) z += w1s[d*28+c]*gr[c];
        z1[((size_t)b*64+d)*PP + p] = z;
        float s = z, q = z*z;
        #pragma unroll
        for (int o = 1; o < 64; o <<= 1) { s += __shfl_xor(s, o, 64); q += __shfl_xor(q, o, 64); }
        if (lane == 0) { wsum[wv][d] = s; wsq[wv][d] = q; }
    }
    __syncthreads();
    if (tid < 64) {
        float s = (wsum[0][tid]+wsum[1][tid])+(wsum[2][tid]+wsum[3][tid]);
        float q = (wsq[0][tid]+wsq[1][tid])+(wsq[2][tid]+wsq[3][tid]);
        size_t blk = (size_t)b*128 + pt;
        part1[(blk*64 + tid)*2+0] = s;
        part1[(blk*64 + tid)*2+1] = q;
    }
}

__global__ __launch_bounds__(256) void k_reduce(const float* __restrict__ part, float* __restrict__ stats, int nch, int nblk, double M) {
    __shared__ double sred[256], qred[256];
    int ch = blockIdx.x, tid = threadIdx.x;
    double s = 0.0, q = 0.0;
    for (int i = tid; i < nblk; i += 256) {
        s += (double)part[((size_t)i*nch + ch)*2 + 0];
        q += (double)part[((size_t)i*nch + ch)*2 + 1];
    }
    sred[tid] = s; qred[tid] = q;
    __syncthreads();
    for (int off = 128; off > 0; off >>= 1) {
        if (tid < off) { sred[tid] += sred[tid+off]; qred[tid] += qred[tid+off]; }
        __syncthreads();
    }
    if (tid == 0) {
        double mu = sred[0] / M;
        double var = qred[0] / M - mu*mu;
        if (var < 0.0) var = 0.0;
        stats[ch*2+0] = (float)mu;
        stats[ch*2+1] = 1.0f / sqrtf((float)var + EPSB);
    }
}

// edge conv1 apply from stored z1
__global__ __launch_bounds__(256) void k_h1(const float* __restrict__ z1,
        const float* __restrict__ st1, const float* __restrict__ g1, const float* __restrict__ be1,
        u64* __restrict__ h1b, u64* __restrict__ h1n) {
    int tid = threadIdx.x;
    int b = blockIdx.y;
    int p0 = blockIdx.x*256;
    int p = p0 + tid;
    int wordbase = (p0>>6) + (tid>>6);
    u64 pm[TT] = {0,0,0,0};
    for (int d = 0; d < 64; ++d) {
        float z = z1[((size_t)b*64+d)*PP + p];
        float mu = st1[d*2+0], iv = st1[d*2+1];
        float v = 0.f;
        #pragma unroll
        for (int t = 0; t < TT; ++t) {
            float y = (z - mu) * iv * g1[t*64+d] + be1[t*64+d];
            float s = lif_step(v, y);
            u64 m = __ballot(s != 0.f);
            if ((tid & 63) == 0) h1b[((size_t)(t*BB+b)*64 + d)*512 + wordbase] = m;
            pm[t] |= ((u64)(s != 0.f)) << d;
        }
    }
    #pragma unroll
    for (int t = 0; t < TT; ++t) h1n[(size_t)(t*BB+b)*PP + p] = pm[t];
}

// ---------------- Tiled popcount Grams (exact int counts) ----------------
__global__ __launch_bounds__(256) void k_gram_h1(const u64* __restrict__ h1b, int* __restrict__ Mi) {
    __shared__ u64 tw[64*65];
    int tid = threadIdx.x;
    int w0 = blockIdx.x*64;
    int tb = blockIdx.y;
    int t = tb >> 3;
    const u64* src = h1b + (size_t)tb*64*512;
    for (int l = tid; l < 64*64; l += 256) {
        int c = l >> 6, w = l & 63;
        tw[c*65+w] = src[(size_t)c*512 + w0 + w];
    }
    __syncthreads();
    int q = tid >> 4, r = tid & 15;
    int acc[4][4];
    #pragma unroll
    for (int i=0;i<4;++i)
        #pragma unroll
        for (int j=0;j<4;++j) acc[i][j]=0;
    #pragma unroll 4
    for (int w = 0; w < 64; ++w) {
        u64 av[4], bv[4];
        #pragma unroll
        for (int i=0;i<4;++i) av[i] = tw[(q+16*i)*65+w];
        #pragma unroll
        for (int j=0;j<4;++j) bv[j] = tw[(r+16*j)*65+w];
        #pragma unroll
        for (int i=0;i<4;++i)
            #pragma unroll
            for (int j=0;j<4;++j) acc[i][j] += (int)__popcll(av[i]&bv[j]);
    }
    #pragma unroll
    for (int i=0;i<4;++i)
        #pragma unroll
        for (int j=0;j<4;++j)
            atomicAdd(&Mi[((size_t)t*64 + q+16*i)*64 + r+16*j], acc[i][j]);
}

template<int C>
__global__ __launch_bounds__(256) void k_gram2(const u64* __restrict__ bits, int* __restrict__ Mi) {
    __shared__ u64 ta[64*33], tbt[64*33];
    int tid = threadIdx.x;
    int ci0 = blockIdx.x*64, cj0 = blockIdx.y*64;
    int tb = blockIdx.z;
    int t = tb >> 3;
    const u64* srcA = bits + ((size_t)tb*C + ci0)*32;
    const u64* srcB = bits + ((size_t)tb*C + cj0)*32;
    for (int l = tid; l < 64*32; l += 256) {
        int rr = l >> 5, w = l & 31;
        ta[rr*33+w]  = srcA[(size_t)rr*32+w];
        tbt[rr*33+w] = srcB[(size_t)rr*32+w];
    }
    __syncthreads();
    int q = tid >> 4, r = tid & 15;
    int acc[4][4];
    #pragma unroll
    for (int i=0;i<4;++i)
        #pragma unroll
        for (int j=0;j<4;++j) acc[i][j]=0;
    #pragma unroll 4
    for (int w = 0; w < 32; ++w) {
        u64 av[4], bv[4];
        #pragma unroll
        for (int i=0;i<4;++i) av[i] = ta[(q+16*i)*33+w];
        #pragma unroll
        for (int j=0;j<4;++j) bv[j] = tbt[(r+16*j)*33+w];
        #pragma unroll
        for (int i=0;i<4;++i)
            #pragma unroll
            for (int j=0;j<4;++j) acc[i][j] += (int)__popcll(av[i]&bv[j]);
    }
    #pragma unroll
    for (int i=0;i<4;++i)
        #pragma unroll
        for (int j=0;j<4;++j)
            atomicAdd(&Mi[((size_t)t*C + ci0+q+16*i)*C + cj0+r+16*j], acc[i][j]);
}

// project int Gram through weights -> per-(t,ch) (mean, inv_std)
template<int CIN>
__global__ void k_proj(const int* __restrict__ Mf, const float* __restrict__ w,
        float* __restrict__ st, int COUT, double cnt) {
    __shared__ double z2s[256], mns[256];
    int ch = blockIdx.x, t = blockIdx.y, c2 = threadIdx.x;
    const int* Mt = Mf + (size_t)t*CIN*CIN;
    double y = 0.0;
    for (int c = 0; c < CIN; ++c)
        y += (double)w[(size_t)ch*CIN+c] * (double)Mt[(size_t)c*CIN + c2];
    double wc2 = (double)w[(size_t)ch*CIN+c2];
    z2s[c2] = wc2 * y;
    mns[c2] = wc2 * (double)Mt[(size_t)c2*CIN + c2];
    __syncthreads();
    for (int off = CIN>>1; off > 0; off >>= 1) {
        if (c2 < off) { z2s[c2] += z2s[c2+off]; mns[c2] += mns[c2+off]; }
        __syncthreads();
    }
    if (c2 == 0) {
        double mu = mns[0] / cnt;
        double var = z2s[0] / cnt - mu*mu;
        if (var < 0.0) var = 0.0;
        st[((size_t)t*COUT+ch)*2+0] = (float)mu;
        st[((size_t)t*COUT+ch)*2+1] = 1.0f / sqrtf((float)var + EPSB);
    }
}

// weight prep: fp32 w[F][K] -> exact 3-way bf16 split in MFMA-frag layout [K/8][F][8]
__global__ __launch_bounds__(256) void k_wprep(const float* __restrict__ w,
        short* __restrict__ hi, short* __restrict__ mid, short* __restrict__ lo, int F, int K) {
    int i = blockIdx.x*256 + threadIdx.x;
    if (i >= F*K) return;
    int f = i / K, k = i % K;
    float wv = w[i];
    u32 b0 = __float_as_uint(wv);
    float h = __uint_as_float(b0 & 0xFFFF0000u);
    float r1 = wv - h;
    u32 b1 = __float_as_uint(r1);
    float m = __uint_as_float(b1 & 0xFFFF0000u);
    float r2 = r1 - m;
    u32 b2 = __float_as_uint(r2);
    size_t o = ((size_t)(k>>3)*F + f)*8 + (k&7);
    hi[o]  = (short)(b0 >> 16);
    mid[o] = (short)(b1 >> 16);
    lo[o]  = (short)(b2 >> 16);
}

// ---------------- MFMA spike conv (KT=64 LDS weight tiles + LUT A-expansion) ----------------
template<int K, int F, int MODE, bool BITS>
__global__ __launch_bounds__(256) void k_mconv(
        const void* __restrict__ Asrc,
        const short* __restrict__ Whi, const short* __restrict__ Wmd, const short* __restrict__ Wlo,
        const float* __restrict__ st, const float* __restrict__ ga, const float* __restrict__ be,
        const float* __restrict__ bias,
        u16* __restrict__ outp, u32* __restrict__ outm, int NPTS) {
    constexpr int KT = 64;
    constexpr int ROWS = (KT/8)*3;
    constexpr int NW = (K+63)/64;
    __shared__ short wsm[ROWS*512];
    __shared__ short sptab[BITS ? 256*8 : 8];
    __shared__ u32 morr[TT][64];
    int tid = threadIdx.x;
    int wave = tid >> 6, lane = tid & 63;
    int l15 = lane & 15, lg = lane >> 4;
    int b = blockIdx.z;
    int n_base = blockIdx.x*64 + wave*16;
    int f0 = blockIdx.y*64;
    if (MODE == 0 || MODE == 2)
        for (int l = tid; l < TT*64; l += 256) morr[l>>6][l&63] = 0u;
    if (BITS) {
        #pragma unroll
        for (int j = 0; j < 8; ++j) sptab[tid*8+j] = (short)(((tid>>j)&1) * 0x3F80);
    }

    f4 acc[4][TT];
    #pragma unroll
    for (int i = 0; i < 4; ++i)
        #pragma unroll
        for (int t = 0; t < TT; ++t) acc[i][t] = (f4)0.f;

    u64 aw[TT][NW];
    const u16* Au[TT];
    #pragma unroll
    for (int t = 0; t < TT; ++t) {
        if (BITS) {
            const u64* Ab = (const u64*)Asrc + ((size_t)(t*BB+b)*NPTS + n_base + l15)*NW;
            #pragma unroll
            for (int wq = 0; wq < NW; ++wq) aw[t][wq] = Ab[wq];
        } else {
            Au[t] = (const u16*)Asrc + ((size_t)(t*BB+b)*NPTS + n_base + l15)*K + lg*8;
        }
    }
    const short* Wsrc[3] = {Whi, Wmd, Wlo};

    #pragma unroll
    for (int kt = 0; kt < K; kt += KT) {
        if (kt > 0) __syncthreads();
        #pragma unroll
        for (int r = wave; r < ROWS; r += 4) {
            int kq = r/3, s = r - kq*3;
            const short* g = Wsrc[s] + ((size_t)((kt>>3) + kq)*F + f0)*8 + lane*8;
            GLOAD_LDS16(g, &wsm[r*512]);
        }
        __syncthreads();
        #pragma unroll
        for (int k0 = 0; k0 < KT; k0 += 32) {
            int kg = kt + k0;
            short8 a[TT];
            #pragma unroll
            for (int t = 0; t < TT; ++t) {
                if (BITS) {
                    u32 byte = (u32)(aw[t][kg>>6] >> ((kg&63) + lg*8)) & 0xFFu;
                    a[t] = *(const short8*)(sptab + byte*8);
                } else {
                    a[t] = *(const short8*)(Au[t] + kg);
                }
            }
            int kql = (k0>>3) + lg;
            #pragma unroll
            for (int fs = 0; fs < 4; ++fs) {
                const short* base = wsm + kql*1536 + (fs*16+l15)*8;
                short8 whi = *(const short8*)(base);
                short8 wmd = *(const short8*)(base + 512);
                short8 wlo = *(const short8*)(base + 1024);
                #pragma unroll
                for (int t = 0; t < TT; ++t) {
                    acc[fs][t] = __builtin_amdgcn_mfma_f32_16x16x32_bf16(a[t], whi, acc[fs][t], 0, 0, 0);
                    acc[fs][t] = __builtin_amdgcn_mfma_f32_16x16x32_bf16(a[t], wmd, acc[fs][t], 0, 0, 0);
                    acc[fs][t] = __builtin_amdgcn_mfma_f32_16x16x32_bf16(a[t], wlo, acc[fs][t], 0, 0, 0);
                }
            }
        }
    }
    if (MODE == 1) {
        #pragma unroll
        for (int fs = 0; fs < 4; ++fs) {
            int f = f0 + fs*16 + l15;
            #pragma unroll
            for (int reg = 0; reg < 4; ++reg) {
                int n = n_base + lg*4 + reg;
                float v = 0.f;
                #pragma unroll
                for (int t = 0; t < TT; ++t) {
                    int ch = t*F + f;
                    float y = (acc[fs][t][reg] - st[(size_t)ch*2+0])*st[(size_t)ch*2+1]*ga[ch] + be[ch];
                    float s = lif_step(v, y);
                    outp[((size_t)(t*BB+b)*NPTS + n)*F + f] = (s != 0.f) ? (u16)0x3F80 : (u16)0;
                }
            }
        }
    } else if (MODE == 3) {
        #pragma unroll
        for (int fs = 0; fs < 4; ++fs) {
            int f = f0 + fs*16 + l15;
            u32 nib = 0u;
            #pragma unroll
            for (int reg = 0; reg < 4; ++reg) {
                float v = 0.f;
                #pragma unroll
                for (int t = 0; t < TT; ++t) {
                    int ch = t*F + f;
                    float y = (acc[fs][t][reg] - st[(size_t)ch*2+0])*st[(size_t)ch*2+1]*ga[ch] + be[ch];
                    float s = lif_step(v, y);
                    if (s != 0.f) nib |= (1u << t);
                }
            }
            nib |= __shfl_xor(nib, 16, 64);
            nib |= __shfl_xor(nib, 32, 64);
            if (lg == 0) {
                int n_pt = n_base >> 4;
                #pragma unroll
                for (int t = 0; t < TT; ++t)
                    outp[((size_t)(t*BB+b)*(NPTS>>4) + n_pt)*F + f] = ((nib>>t)&1u) ? (u16)0x3F80 : (u16)0;
            }
        }
    } else {
        #pragma unroll
        for (int fs = 0; fs < 4; ++fs) {
            int f = f0 + fs*16 + l15;
            u32 any[TT] = {0,0,0,0};
            float bb = (MODE == 0) ? bias[f] : 0.f;
            #pragma unroll
            for (int reg = 0; reg < 4; ++reg) {
                float v = 0.f;
                #pragma unroll
                for (int t = 0; t < TT; ++t) {
                    float y;
                    if (MODE == 0) y = acc[fs][t][reg] + bb;
                    else {
                        int ch = t*F + f;
                        y = (acc[fs][t][reg] - st[(size_t)ch*2+0])*st[(size_t)ch*2+1]*ga[ch] + be[ch];
                    }
                    float s = lif_step(v, y);
                    if (s != 0.f) any[t] = 1u;
                }
            }
            #pragma unroll
            for (int t = 0; t < TT; ++t) if (any[t]) atomicOr(&morr[t][fs*16+l15], 1u);
        }
        __syncthreads();
        for (int l = tid; l < TT*64; l += 256)
            if (morr[l>>6][l&63]) atomicOr(&outm[((size_t)((l>>6)*BB+b))*F + f0 + (l&63)], 1u);
    }
}

// repack point-major bf16-u16 spikes [t][b][n][C] -> channel-major bits [t][b][C][32 words over n]
template<int C>
__global__ __launch_bounds__(256) void k_repack(const u16* __restrict__ sp, u64* __restrict__ bits) {
    __shared__ u16 tile[64][C+2];
    int tid = threadIdx.x;
    int nw = blockIdx.x, b = blockIdx.y, t = blockIdx.z;
    const u16* src = sp + ((size_t)(t*BB+b)*NN + nw*64)*C;
    for (int i = tid*2; i < 64*C; i += 512) {
        u32 v = *(const u32*)(src + i);
        int r = i / C, c = i % C;
        *(u32*)&tile[r][c] = v;
    }
    __syncthreads();
    int wave = tid >> 6, lane = tid & 63;
    for (int c = wave; c < C; c += 4) {
        u64 m = __ballot(tile[lane][c] != 0);
        if (lane == 0) bits[((size_t)(t*BB+b)*C + c)*32 + nw] = m;
    }
}

__global__ __launch_bounds__(256) void k_out(const u32* __restrict__ mx4, float* __restrict__ out) {
    int i = blockIdx.x*256 + threadIdx.x;
    int b = i >> 10, g = i & 1023;
    float s = (float)(mx4[((size_t)0*BB+b)*1024+g] + mx4[((size_t)1*BB+b)*1024+g]
                    + mx4[((size_t)2*BB+b)*1024+g] + mx4[((size_t)3*BB+b)*1024+g]);
    out[i] = s * 0.25f;
}

extern "C" void kernel_launch(void* const* d_in, const int* in_sizes, int n_in,
                              void* d_out, int out_size, void* d_ws, size_t ws_size,
                              hipStream_t stream) {
    (void)in_sizes; (void)n_in; (void)out_size;
    const float* x    = (const float*)d_in[0];
    const float* tw1  = (const float*)d_in[1];
    const float* tb1  = (const float*)d_in[2];
    const float* tw2  = (const float*)d_in[3];
    const float* tb2  = (const float*)d_in[4];
    const float* tw3  = (const float*)d_in[5];
    const float* tb3  = (const float*)d_in[6];
    const float* tfw1 = (const float*)d_in[7];
    const float* tfb1 = (const float*)d_in[8];
    const float* tfw2 = (const float*)d_in[9];
    const float* tfb2 = (const float*)d_in[10];
    const float* tfw3 = (const float*)d_in[11];
    const float* tfb3 = (const float*)d_in[12];
    const float* w1   = (const float*)d_in[13];
    const float* w2   = (const float*)d_in[14];
    const float* w3   = (const float*)d_in[15];
    const float* w4   = (const float*)d_in[16];
    const float* g1   = (const float*)d_in[17];
    const float* be1  = (const float*)d_in[18];
    const float* g2   = (const float*)d_in[19];
    const float* be2  = (const float*)d_in[20];
    const float* g3   = (const float*)d_in[21];
    const float* be3  = (const float*)d_in[22];
    const float* g4   = (const float*)d_in[23];
    const float* be4  = (const float*)d_in[24];

    char* wsb = (char*)d_ws;
    size_t off = 0;
    auto alloc = [&](size_t bytes) -> void* {
        void* p = wsb + off;
        off = (off + bytes + 255) & ~(size_t)255;
        return p;
    };
    u64* s1b   = (u64*)alloc(sizeof(u64)*(size_t)TT*BB*NN);
    u64* s2b   = (u64*)alloc(sizeof(u64)*(size_t)TT*BB*NN*2);
    // mx and mx4 contiguous -> single memset covers both (each 256B-aligned size)
    u32* mx    = (u32*)alloc(sizeof(u32)*(size_t)TT*BB*1024);
    u32* mx4   = (u32*)alloc(sizeof(u32)*(size_t)TT*BB*1024);
    float* trs = (float*)alloc(sizeof(float)*BB*9);
    float* xa  = (float*)alloc(sizeof(float)*(size_t)BB*14*NN);
    float4* xa4 = (float4*)alloc(sizeof(float4)*(size_t)BB*NN);
    int* idx   = (int*)alloc(sizeof(int)*(size_t)BB*NN*KNB);
    float* z1  = (float*)alloc(sizeof(float)*(size_t)BB*64*PP);
    float* part1 = (float*)alloc(sizeof(float)*(size_t)1024*64*2);
    float* st1 = (float*)alloc(sizeof(float)*64*2);
    float* st2 = (float*)alloc(sizeof(float)*512*2);
    float* st3 = (float*)alloc(sizeof(float)*1024*2);
    float* st4 = (float*)alloc(sizeof(float)*4096*2);
    float* h1v = (float*)alloc(sizeof(float)*(size_t)TT*BB*512);
    float* h2v = (float*)alloc(sizeof(float)*(size_t)TT*BB*256);
    u64* h1b = (u64*)alloc(sizeof(u64)*(size_t)TT*BB*64*512);
    u64* h1n = (u64*)alloc(sizeof(u64)*(size_t)TT*BB*PP);
    u16* m2p = (u16*)alloc(sizeof(u16)*(size_t)TT*BB*NN*128);
    u16* h3p = (u16*)alloc(sizeof(u16)*(size_t)TT*BB*NN*256);
    u64* m2b = (u64*)alloc(sizeof(u64)*(size_t)TT*BB*128*32);
    u64* h3b = (u64*)alloc(sizeof(u64)*(size_t)TT*BB*256*32);
    // Gram buffers contiguous -> single memset covers all three
    int* Mi64  = (int*)alloc(sizeof(int)*(size_t)TT*64*64);
    int* Mi128 = (int*)alloc(sizeof(int)*(size_t)TT*128*128);
    int* Mi256 = (int*)alloc(sizeof(int)*(size_t)TT*256*256);
    short* wp2h = (short*)alloc(sizeof(short)*(size_t)128*64);
    short* wp2m = (short*)alloc(sizeof(short)*(size_t)128*64);
    short* wp2l = (short*)alloc(sizeof(short)*(size_t)128*64);
    short* wp3h = (short*)alloc(sizeof(short)*(size_t)256*128);
    short* wp3m = (short*)alloc(sizeof(short)*(size_t)256*128);
    short* wp3l = (short*)alloc(sizeof(short)*(size_t)256*128);
    short* wp4h = (short*)alloc(sizeof(short)*(size_t)1024*256);
    short* wp4m = (short*)alloc(sizeof(short)*(size_t)1024*256);
    short* wp4l = (short*)alloc(sizeof(short)*(size_t)1024*256);
    short* wpth = (short*)alloc(sizeof(short)*(size_t)1024*128);
    short* wptm = (short*)alloc(sizeof(short)*(size_t)1024*128);
    short* wptl = (short*)alloc(sizeof(short)*(size_t)1024*128);
    if (off > ws_size) return;

    // merged memsets (buffers are contiguous & 256B-size-aligned)
    hipMemsetAsync(mx, 0, sizeof(u32)*(size_t)TT*BB*1024*2, stream);
    hipMemsetAsync(Mi64, 0, sizeof(int)*((size_t)TT*64*64 + (size_t)TT*128*128 + (size_t)TT*256*256), stream);

    // weight prep (exact 3-way bf16 split)
    k_wprep<<<dim3((128*64+255)/256), dim3(256), 0, stream>>>(w2, wp2h, wp2m, wp2l, 128, 64);
    k_wprep<<<dim3((256*128+255)/256), dim3(256), 0, stream>>>(w3, wp3h, wp3m, wp3l, 256, 128);
    k_wprep<<<dim3((1024*256+255)/256), dim3(256), 0, stream>>>(w4, wp4h, wp4m, wp4l, 1024, 256);
    k_wprep<<<dim3((1024*128+255)/256), dim3(256), 0, stream>>>(tw3, wpth, wptm, wptl, 1024, 128);

    // T-Net
    k_tnet1<<<dim3(64), dim3(256), 0, stream>>>(x, tw1, tb1, s1b);
    k_tnet2<<<dim3(64, 4), dim3(256), 0, stream>>>(s1b, tw2, tb2, (u32*)s2b);
    k_mconv<128,1024,0,true><<<dim3(32,16,8), dim3(256), 0, stream>>>(
        s2b, wpth, wptm, wptl, nullptr, nullptr, nullptr, tb3, nullptr, mx, NN);
    k_fc1<<<dim3(512, 8), dim3(64), 0, stream>>>(mx, tfw1, tfb1, h1v);
    k_fc2<<<dim3(256, 8), dim3(64), 0, stream>>>(h1v, tfw2, tfb2, h2v);
    k_fc3<<<dim3(8), dim3(64), 0, stream>>>(h2v, tfw3, tfb3, trs);
    k_trans<<<dim3(64), dim3(256), 0, stream>>>(x, trs, xa, xa4);
    // KNN (wave-per-query)
    k_knn<<<dim3(NN/4, BB), dim3(256), 0, stream>>>(xa4, idx);
    // fused graph-feature + edge conv1 GEMM (z once) + stats partials
    k_zstats<<<dim3(128, 8), dim3(256), 0, stream>>>(xa, idx, w1, part1, z1);
    k_reduce<<<dim3(64), dim3(256), 0, stream>>>(part1, st1, 64, 1024, 262144.0);
    k_h1<<<dim3(128, 8), dim3(256), 0, stream>>>(z1, st1, g1, be1, h1b, h1n);
    // edge conv2: stats via tiled Gram, apply via MFMA (+ max over k)
    k_gram_h1<<<dim3(8, TT*BB), dim3(256), 0, stream>>>(h1b, Mi64);
    k_proj<64><<<dim3(128, TT), dim3(64), 0, stream>>>(Mi64, w2, st2, 128, 262144.0);
    k_mconv<64,128,3,true><<<dim3(PP/64,2,8), dim3(256), 0, stream>>>(
        h1n, wp2h, wp2m, wp2l, st2, g2, be2, nullptr, m2p, nullptr, PP);
    k_repack<128><<<dim3(32,8,4), dim3(256), 0, stream>>>(m2p, m2b);
    // conv3
    k_gram2<128><<<dim3(2,2,TT*BB), dim3(256), 0, stream>>>(m2b, Mi128);
    k_proj<128><<<dim3(256, TT), dim3(128), 0, stream>>>(Mi128, w3, st3, 256, 16384.0);
    k_mconv<128,256,1,false><<<dim3(32,4,8), dim3(256), 0, stream>>>(
        m2p, wp3h, wp3m, wp3l, st3, g3, be3, nullptr, h3p, nullptr, NN);
    k_repack<256><<<dim3(32,8,4), dim3(256), 0, stream>>>(h3p, h3b);
    // conv4
    k_gram2<256><<<dim3(4,4,TT*BB), dim3(256), 0, stream>>>(h3b, Mi256);
    k_proj<256><<<dim3(1024, TT), dim3(256), 0, stream>>>(Mi256, w4, st4, 1024, 16384.0);
    k_mconv<256,1024,2,false><<<dim3(32,16,8), dim3(256), 0, stream>>>(
        h3p, wp4h, wp4m, wp4l, st4, g4, be4, nullptr, nullptr, mx4, NN);
    // output
    k_out<<<dim3(32), dim3(256), 0, stream>>>(mx4, (float*)d_out);
}

// Round 13
// 712.528 us; speedup vs baseline: 1.1311x; 1.0072x over previous
//
#include <hip/hip_runtime.h>
#include <stdint.h>

#define TT 4
#define BB 8
#define NN 2048
#define KNB 16
#define PP (NN*KNB)
#define VTH 1.0f
#define EPSB 1e-5f

typedef unsigned long long u64;
typedef unsigned int u32;
typedef unsigned short u16;
typedef unsigned char u8;
typedef __attribute__((ext_vector_type(8))) short short8;
typedef __attribute__((ext_vector_type(4))) float f4;

#define GLOAD_LDS16(g, l) __builtin_amdgcn_global_load_lds( \
    (const __attribute__((address_space(1))) u32*)(g), \
    (__attribute__((address_space(3))) u32*)(l), 16, 0, 0)

__device__ __forceinline__ float lif_step(float& v, float x) {
    v = v + (x - v) / 2.0f;
    float s = (v - VTH >= 0.0f) ? 1.0f : 0.0f;
    v = v * (1.0f - s);
    return s;
}

// ---------------- T-Net ----------------
__global__ __launch_bounds__(256) void k_tnet1(const float* __restrict__ x, const float* __restrict__ w,
        const float* __restrict__ bi, u64* __restrict__ s1b) {
    int i = blockIdx.x*256 + threadIdx.x;
    int b = i >> 11, n = i & 2047;
    float p0 = x[((size_t)b*14+0)*NN+n];
    float p1 = x[((size_t)b*14+1)*NN+n];
    float p2 = x[((size_t)b*14+2)*NN+n];
    u64 m[TT] = {0,0,0,0};
    for (int d = 0; d < 64; ++d) {
        float z = ((w[d*3+0]*p0 + w[d*3+1]*p1) + w[d*3+2]*p2) + bi[d];
        float v = 0.f;
        #pragma unroll
        for (int t = 0; t < TT; ++t) {
            float s = lif_step(v, z);
            if (s != 0.f) m[t] |= (1ull << d);
        }
    }
    #pragma unroll
    for (int t = 0; t < TT; ++t) s1b[((size_t)t*BB + b)*NN + n] = m[t];
}

// conv2: 64->128, split over 4 channel-chunks of 32 for occupancy
__global__ __launch_bounds__(256) void k_tnet2(const u64* __restrict__ s1b, const float* __restrict__ w,
        const float* __restrict__ bi, u32* __restrict__ s2b32) {
    __shared__ float ws[32*64];
    int tid = threadIdx.x;
    int ec = blockIdx.y;
    for (int l = tid; l < 32*64; l += 256) ws[l] = w[ec*32*64 + l];
    __syncthreads();
    int i = blockIdx.x*256 + tid;
    int b = i >> 11, n = i & 2047;
    u64 m[TT];
    #pragma unroll
    for (int t = 0; t < TT; ++t) m[t] = s1b[((size_t)t*BB+b)*NN+n];
    u32 o[TT] = {0,0,0,0};
    for (int el = 0; el < 32; ++el) {
        float z[TT] = {0.f,0.f,0.f,0.f};
        #pragma unroll 8
        for (int d = 0; d < 64; ++d) {
            float wv = ws[el*64+d];
            #pragma unroll
            for (int t = 0; t < TT; ++t) z[t] += ((m[t]>>d)&1ull) ? wv : 0.f;
        }
        float v = 0.f, bb = bi[ec*32 + el];
        #pragma unroll
        for (int t = 0; t < TT; ++t) {
            float s = lif_step(v, z[t] + bb);
            if (s != 0.f) o[t] |= (1u << el);
        }
    }
    #pragma unroll
    for (int t = 0; t < TT; ++t)
        s2b32[(((size_t)t*BB+b)*NN+n)*4 + ec] = o[t];
}

// FC head, wave-parallel
__global__ __launch_bounds__(64) void k_fc1(const u32* __restrict__ mx, const float* __restrict__ fw1,
        const float* __restrict__ fb1, float* __restrict__ h1v) {
    int f = blockIdx.x, b = blockIdx.y, lane = threadIdx.x;
    float wr[16];
    #pragma unroll
    for (int j = 0; j < 16; ++j) wr[j] = fw1[(size_t)f*1024 + j*64 + lane];
    float z[TT];
    #pragma unroll
    for (int t = 0; t < TT; ++t) {
        float s = 0.f;
        #pragma unroll
        for (int j = 0; j < 16; ++j)
            s += wr[j] * (float)mx[((size_t)t*BB+b)*1024 + j*64 + lane];
        #pragma unroll
        for (int o = 1; o < 64; o <<= 1) s += __shfl_xor(s, o, 64);
        z[t] = s;
    }
    if (lane == 0) {
        float v = 0.f;
        #pragma unroll
        for (int t = 0; t < TT; ++t)
            h1v[((size_t)t*BB+b)*512 + f] = lif_step(v, z[t] + fb1[f]);
    }
}

__global__ __launch_bounds__(64) void k_fc2(const float* __restrict__ h1v, const float* __restrict__ fw2,
        const float* __restrict__ fb2, float* __restrict__ h2v) {
    int f = blockIdx.x, b = blockIdx.y, lane = threadIdx.x;
    float wr[8];
    #pragma unroll
    for (int j = 0; j < 8; ++j) wr[j] = fw2[(size_t)f*512 + j*64 + lane];
    float z[TT];
    #pragma unroll
    for (int t = 0; t < TT; ++t) {
        float s = 0.f;
        #pragma unroll
        for (int j = 0; j < 8; ++j)
            s += wr[j] * h1v[((size_t)t*BB+b)*512 + j*64 + lane];
        #pragma unroll
        for (int o = 1; o < 64; o <<= 1) s += __shfl_xor(s, o, 64);
        z[t] = s;
    }
    if (lane == 0) {
        float v = 0.f;
        #pragma unroll
        for (int t = 0; t < TT; ++t)
            h2v[((size_t)t*BB+b)*256 + f] = lif_step(v, z[t] + fb2[f]);
    }
}

__global__ __launch_bounds__(64) void k_fc3(const float* __restrict__ h2v, const float* __restrict__ fw3,
        const float* __restrict__ fb3, float* __restrict__ trans) {
    __shared__ float h3s[TT][9];
    int b = blockIdx.x, tid = threadIdx.x;
    if (tid < TT*9) {
        int t = tid/9, oo = tid%9;
        float z = 0.f;
        for (int c = 0; c < 256; ++c) z += fw3[oo*256+c]*h2v[((size_t)t*BB+b)*256 + c];
        h3s[t][oo] = z + fb3[oo];
    }
    __syncthreads();
    if (tid < 9) {
        float m = ((h3s[0][tid]+h3s[1][tid]) + (h3s[2][tid]+h3s[3][tid])) * 0.25f;
        int c = tid/3, dd = tid%3;
        trans[b*9+tid] = m + ((c==dd)?1.0f:0.0f);
    }
}

// apply transform; also emit packed float4 (x,y,z,sq) for KNN
__global__ __launch_bounds__(256) void k_trans(const float* __restrict__ x, const float* __restrict__ tr,
        float* __restrict__ xa, float4* __restrict__ xa4) {
    int i = blockIdx.x*256 + threadIdx.x;
    int b = i >> 11, n = i & 2047;
    float p0 = x[((size_t)b*14+0)*NN+n];
    float p1 = x[((size_t)b*14+1)*NN+n];
    float p2 = x[((size_t)b*14+2)*NN+n];
    const float* tb = tr + b*9;
    float a0 = (p0*tb[0] + p1*tb[3]) + p2*tb[6];
    float a1 = (p0*tb[1] + p1*tb[4]) + p2*tb[7];
    float a2 = (p0*tb[2] + p1*tb[5]) + p2*tb[8];
    xa[((size_t)b*14+0)*NN+n] = a0;
    xa[((size_t)b*14+1)*NN+n] = a1;
    xa[((size_t)b*14+2)*NN+n] = a2;
    for (int c = 3; c < 14; ++c) xa[((size_t)b*14+c)*NN+n] = x[((size_t)b*14+c)*NN+n];
    float4 p;
    p.x = a0; p.y = a1; p.z = a2;
    p.w = (a0*a0 + a1*a1) + a2*a2;
    xa4[(size_t)b*NN+n] = p;
}

// KNN: one wave per query point
__global__ __launch_bounds__(256) void k_knn(const float4* __restrict__ xa4, int* __restrict__ idx) {
    int wave = threadIdx.x >> 6, lane = threadIdx.x & 63;
    int b = blockIdx.y;
    int n = blockIdx.x*4 + wave;
    const float4* P = xa4 + (size_t)b*NN;
    float4 q = P[n];
    float sn = q.w;
    float vals[32];
    #pragma unroll
    for (int j = 0; j < 32; ++j) {
        float4 p = P[j*64 + lane];
        float inner = (q.x*p.x + q.y*p.y) + q.z*p.z;
        vals[j] = (2.0f*inner - sn) - p.w;
    }
    for (int k = 0; k < KNB; ++k) {
        float bv = -3.4e38f; int bj = 0;
        #pragma unroll
        for (int j = 0; j < 32; ++j) if (vals[j] > bv) { bv = vals[j]; bj = j; }
        int bm = bj*64 + lane;
        u32 fb = __float_as_uint(bv);
        fb = (fb & 0x80000000u) ? ~fb : (fb | 0x80000000u);
        u64 key = ((u64)fb << 32) | (u32)(~bm);
        #pragma unroll
        for (int o2 = 1; o2 < 64; o2 <<= 1) {
            u64 other = __shfl_xor(key, o2, 64);
            key = (other > key) ? other : key;
        }
        int wm = (int)(~(u32)key);
        if (lane == 0) idx[((size_t)b*NN + n)*KNB + k] = wm;
        int wl = wm & 63, wj = wm >> 6;
        if (lane == wl) {
            #pragma unroll
            for (int j = 0; j < 32; ++j) if (j == wj) vals[j] = -3.4e38f;
        }
    }
}

// fused graph-feature + edge conv1 GEMM: z once + stats partials (bit-identical z)
__global__ __launch_bounds__(256) void k_zstats(const float* __restrict__ xa, const int* __restrict__ idx,
        const float* __restrict__ w1, float* __restrict__ part1, float* __restrict__ z1) {
    __shared__ float w1s[64*28];
    __shared__ float wsum[4][64], wsq[4][64];
    int pt = blockIdx.x, b = blockIdx.y;
    int p0 = pt*256, tid = threadIdx.x;
    int p = p0 + tid;
    for (int l = tid; l < 64*28; l += 256) w1s[l] = w1[l];
    __syncthreads();
    int n = p >> 4;
    int mm = idx[((size_t)b*NN+n)*KNB + (p & 15)];
    float gr[28];
    #pragma unroll
    for (int c = 0; c < 14; ++c) {
        float ctr = xa[((size_t)b*14+c)*NN + n];
        float nb  = xa[((size_t)b*14+c)*NN + mm];
        gr[c] = ctr;
        gr[14+c] = nb - ctr;
    }
    int wv = tid>>6, lane = tid&63;
    for (int d = 0; d < 64; ++d) {
        float z = 0.f;
        #pragma unroll
        for (int c = 0; c < 28; ++c) z += w1s[d*28+c]*gr[c];
        z1[((size_t)b*64+d)*PP + p] = z;
        float s = z, q = z*z;
        #pragma unroll
        for (int o = 1; o < 64; o <<= 1) { s += __shfl_xor(s, o, 64); q += __shfl_xor(q, o, 64); }
        if (lane == 0) { wsum[wv][d] = s; wsq[wv][d] = q; }
    }
    __syncthreads();
    if (tid < 64) {
        float s = (wsum[0][tid]+wsum[1][tid])+(wsum[2][tid]+wsum[3][tid]);
        float q = (wsq[0][tid]+wsq[1][tid])+(wsq[2][tid]+wsq[3][tid]);
        size_t blk = (size_t)b*128 + pt;
        part1[(blk*64 + tid)*2+0] = s;
        part1[(blk*64 + tid)*2+1] = q;
    }
}

__global__ __launch_bounds__(256) void k_reduce(const float* __restrict__ part, float* __restrict__ stats, int nch, int nblk, double M) {
    __shared__ double sred[256], qred[256];
    int ch = blockIdx.x, tid = threadIdx.x;
    double s = 0.0, q = 0.0;
    for (int i = tid; i < nblk; i += 256) {
        s += (double)part[((size_t)i*nch + ch)*2 + 0];
        q += (double)part[((size_t)i*nch + ch)*2 + 1];
    }
    sred[tid] = s; qred[tid] = q;
    __syncthreads();
    for (int off = 128; off > 0; off >>= 1) {
        if (tid < off) { sred[tid] += sred[tid+off]; qred[tid] += qred[tid+off]; }
        __syncthreads();
    }
    if (tid == 0) {
        double mu = sred[0] / M;
        double var = qred[0] / M - mu*mu;
        if (var < 0.0) var = 0.0;
        stats[ch*2+0] = (float)mu;
        stats[ch*2+1] = 1.0f / sqrtf((float)var + EPSB);
    }
}

// edge conv1 apply from stored z1
__global__ __launch_bounds__(256) void k_h1(const float* __restrict__ z1,
        const float* __restrict__ st1, const float* __restrict__ g1, const float* __restrict__ be1,
        u64* __restrict__ h1b, u64* __restrict__ h1n) {
    int tid = threadIdx.x;
    int b = blockIdx.y;
    int p0 = blockIdx.x*256;
    int p = p0 + tid;
    int wordbase = (p0>>6) + (tid>>6);
    u64 pm[TT] = {0,0,0,0};
    for (int d = 0; d < 64; ++d) {
        float z = z1[((size_t)b*64+d)*PP + p];
        float mu = st1[d*2+0], iv = st1[d*2+1];
        float v = 0.f;
        #pragma unroll
        for (int t = 0; t < TT; ++t) {
            float y = (z - mu) * iv * g1[t*64+d] + be1[t*64+d];
            float s = lif_step(v, y);
            u64 m = __ballot(s != 0.f);
            if ((tid & 63) == 0) h1b[((size_t)(t*BB+b)*64 + d)*512 + wordbase] = m;
            pm[t] |= ((u64)(s != 0.f)) << d;
        }
    }
    #pragma unroll
    for (int t = 0; t < TT; ++t) h1n[(size_t)(t*BB+b)*PP + p] = pm[t];
}

// ---------------- Tiled popcount Grams (exact int counts) ----------------
__global__ __launch_bounds__(256) void k_gram_h1(const u64* __restrict__ h1b, int* __restrict__ Mi) {
    __shared__ u64 tw[64*65];
    int tid = threadIdx.x;
    int w0 = blockIdx.x*64;
    int tb = blockIdx.y;
    int t = tb >> 3;
    const u64* src = h1b + (size_t)tb*64*512;
    for (int l = tid; l < 64*64; l += 256) {
        int c = l >> 6, w = l & 63;
        tw[c*65+w] = src[(size_t)c*512 + w0 + w];
    }
    __syncthreads();
    int q = tid >> 4, r = tid & 15;
    int acc[4][4];
    #pragma unroll
    for (int i=0;i<4;++i)
        #pragma unroll
        for (int j=0;j<4;++j) acc[i][j]=0;
    #pragma unroll 4
    for (int w = 0; w < 64; ++w) {
        u64 av[4], bv[4];
        #pragma unroll
        for (int i=0;i<4;++i) av[i] = tw[(q+16*i)*65+w];
        #pragma unroll
        for (int j=0;j<4;++j) bv[j] = tw[(r+16*j)*65+w];
        #pragma unroll
        for (int i=0;i<4;++i)
            #pragma unroll
            for (int j=0;j<4;++j) acc[i][j] += (int)__popcll(av[i]&bv[j]);
    }
    #pragma unroll
    for (int i=0;i<4;++i)
        #pragma unroll
        for (int j=0;j<4;++j)
            atomicAdd(&Mi[((size_t)t*64 + q+16*i)*64 + r+16*j], acc[i][j]);
}

template<int C>
__global__ __launch_bounds__(256) void k_gram2(const u64* __restrict__ bits, int* __restrict__ Mi) {
    __shared__ u64 ta[64*33], tbt[64*33];
    int tid = threadIdx.x;
    int ci0 = blockIdx.x*64, cj0 = blockIdx.y*64;
    int tb = blockIdx.z;
    int t = tb >> 3;
    const u64* srcA = bits + ((size_t)tb*C + ci0)*32;
    const u64* srcB = bits + ((size_t)tb*C + cj0)*32;
    for (int l = tid; l < 64*32; l += 256) {
        int rr = l >> 5, w = l & 31;
        ta[rr*33+w]  = srcA[(size_t)rr*32+w];
        tbt[rr*33+w] = srcB[(size_t)rr*32+w];
    }
    __syncthreads();
    int q = tid >> 4, r = tid & 15;
    int acc[4][4];
    #pragma unroll
    for (int i=0;i<4;++i)
        #pragma unroll
        for (int j=0;j<4;++j) acc[i][j]=0;
    #pragma unroll 4
    for (int w = 0; w < 32; ++w) {
        u64 av[4], bv[4];
        #pragma unroll
        for (int i=0;i<4;++i) av[i] = ta[(q+16*i)*33+w];
        #pragma unroll
        for (int j=0;j<4;++j) bv[j] = tbt[(r+16*j)*33+w];
        #pragma unroll
        for (int i=0;i<4;++i)
            #pragma unroll
            for (int j=0;j<4;++j) acc[i][j] += (int)__popcll(av[i]&bv[j]);
    }
    #pragma unroll
    for (int i=0;i<4;++i)
        #pragma unroll
        for (int j=0;j<4;++j)
            atomicAdd(&Mi[((size_t)t*C + ci0+q+16*i)*C + cj0+r+16*j], acc[i][j]);
}

// project int Gram through weights -> per-(t,ch) (mean, inv_std)
template<int CIN>
__global__ void k_proj(const int* __restrict__ Mf, const float* __restrict__ w,
        float* __restrict__ st, int COUT, double cnt) {
    __shared__ double z2s[256], mns[256];
    int ch = blockIdx.x, t = blockIdx.y, c2 = threadIdx.x;
    const int* Mt = Mf + (size_t)t*CIN*CIN;
    double y = 0.0;
    for (int c = 0; c < CIN; ++c)
        y += (double)w[(size_t)ch*CIN+c] * (double)Mt[(size_t)c*CIN + c2];
    double wc2 = (double)w[(size_t)ch*CIN+c2];
    z2s[c2] = wc2 * y;
    mns[c2] = wc2 * (double)Mt[(size_t)c2*CIN + c2];
    __syncthreads();
    for (int off = CIN>>1; off > 0; off >>= 1) {
        if (c2 < off) { z2s[c2] += z2s[c2+off]; mns[c2] += mns[c2+off]; }
        __syncthreads();
    }
    if (c2 == 0) {
        double mu = mns[0] / cnt;
        double var = z2s[0] / cnt - mu*mu;
        if (var < 0.0) var = 0.0;
        st[((size_t)t*COUT+ch)*2+0] = (float)mu;
        st[((size_t)t*COUT+ch)*2+1] = 1.0f / sqrtf((float)var + EPSB);
    }
}

// merged weight prep: all four fp32 weight tensors -> exact 3-way bf16 split [K/8][F][8]
__global__ __launch_bounds__(256) void k_wprep_all(
        const float* __restrict__ w2, const float* __restrict__ w3,
        const float* __restrict__ w4, const float* __restrict__ tw3,
        short* __restrict__ h2, short* __restrict__ m2s, short* __restrict__ l2,
        short* __restrict__ h3, short* __restrict__ m3s, short* __restrict__ l3,
        short* __restrict__ h4, short* __restrict__ m4s, short* __restrict__ l4,
        short* __restrict__ ht, short* __restrict__ mts, short* __restrict__ lt) {
    int i = blockIdx.x*256 + threadIdx.x;
    const float* w; short *hi, *mid, *lo; int F, ks;
    if (i < 8192)        {            w = w2;  hi=h2; mid=m2s; lo=l2; F=128;  ks=6; }
    else if (i < 40960)  { i -= 8192;  w = w3;  hi=h3; mid=m3s; lo=l3; F=256;  ks=7; }
    else if (i < 303104) { i -= 40960; w = w4;  hi=h4; mid=m4s; lo=l4; F=1024; ks=8; }
    else if (i < 434176) { i -= 303104; w = tw3; hi=ht; mid=mts; lo=lt; F=1024; ks=7; }
    else return;
    int f = i >> ks, k = i & ((1<<ks)-1);
    float wv = w[i];
    u32 b0 = __float_as_uint(wv);
    float h = __uint_as_float(b0 & 0xFFFF0000u);
    float r1 = wv - h;
    u32 b1 = __float_as_uint(r1);
    float m = __uint_as_float(b1 & 0xFFFF0000u);
    float r2 = r1 - m;
    u32 b2 = __float_as_uint(r2);
    size_t o = ((size_t)(k>>3)*F + f)*8 + (k&7);
    hi[o]  = (short)(b0 >> 16);
    mid[o] = (short)(b1 >> 16);
    lo[o]  = (short)(b2 >> 16);
}

// ---------------- MFMA spike conv (KT=64 LDS weight tiles + LUT A-expansion) ----------------
// MODE 1 additionally emits channel-major ballot bits (fused repack): block covers exactly
// 64 n x 64 f, so per-t LDS stage + __ballot reproduces k_repack's words bit-identically.
template<int K, int F, int MODE, bool BITS>
__global__ __launch_bounds__(256) void k_mconv(
        const void* __restrict__ Asrc,
        const short* __restrict__ Whi, const short* __restrict__ Wmd, const short* __restrict__ Wlo,
        const float* __restrict__ st, const float* __restrict__ ga, const float* __restrict__ be,
        const float* __restrict__ bias,
        u16* __restrict__ outp, u32* __restrict__ outm, u64* __restrict__ outb, int NPTS) {
    constexpr int KT = 64;
    constexpr int ROWS = (KT/8)*3;
    constexpr int NW = (K+63)/64;
    __shared__ short wsm[ROWS*512];
    __shared__ short sptab[BITS ? 256*8 : 8];
    __shared__ u32 morr[TT][64];
    __shared__ u8 btile[(MODE==1) ? 64*68 : 4];
    int tid = threadIdx.x;
    int wave = tid >> 6, lane = tid & 63;
    int l15 = lane & 15, lg = lane >> 4;
    int b = blockIdx.z;
    int n_base = blockIdx.x*64 + wave*16;
    int f0 = blockIdx.y*64;
    if (MODE == 0 || MODE == 2)
        for (int l = tid; l < TT*64; l += 256) morr[l>>6][l&63] = 0u;
    if (BITS) {
        #pragma unroll
        for (int j = 0; j < 8; ++j) sptab[tid*8+j] = (short)(((tid>>j)&1) * 0x3F80);
    }

    f4 acc[4][TT];
    #pragma unroll
    for (int i = 0; i < 4; ++i)
        #pragma unroll
        for (int t = 0; t < TT; ++t) acc[i][t] = (f4)0.f;

    u64 aw[TT][NW];
    const u16* Au[TT];
    #pragma unroll
    for (int t = 0; t < TT; ++t) {
        if (BITS) {
            const u64* Ab = (const u64*)Asrc + ((size_t)(t*BB+b)*NPTS + n_base + l15)*NW;
            #pragma unroll
            for (int wq = 0; wq < NW; ++wq) aw[t][wq] = Ab[wq];
        } else {
            Au[t] = (const u16*)Asrc + ((size_t)(t*BB+b)*NPTS + n_base + l15)*K + lg*8;
        }
    }
    const short* Wsrc[3] = {Whi, Wmd, Wlo};

    #pragma unroll
    for (int kt = 0; kt < K; kt += KT) {
        if (kt > 0) __syncthreads();
        #pragma unroll
        for (int r = wave; r < ROWS; r += 4) {
            int kq = r/3, s = r - kq*3;
            const short* g = Wsrc[s] + ((size_t)((kt>>3) + kq)*F + f0)*8 + lane*8;
            GLOAD_LDS16(g, &wsm[r*512]);
        }
        __syncthreads();
        #pragma unroll
        for (int k0 = 0; k0 < KT; k0 += 32) {
            int kg = kt + k0;
            short8 a[TT];
            #pragma unroll
            for (int t = 0; t < TT; ++t) {
                if (BITS) {
                    u32 byte = (u32)(aw[t][kg>>6] >> ((kg&63) + lg*8)) & 0xFFu;
                    a[t] = *(const short8*)(sptab + byte*8);
                } else {
                    a[t] = *(const short8*)(Au[t] + kg);
                }
            }
            int kql = (k0>>3) + lg;
            #pragma unroll
            for (int fs = 0; fs < 4; ++fs) {
                const short* base = wsm + kql*1536 + (fs*16+l15)*8;
                short8 whi = *(const short8*)(base);
                short8 wmd = *(const short8*)(base + 512);
                short8 wlo = *(const short8*)(base + 1024);
                #pragma unroll
                for (int t = 0; t < TT; ++t) {
                    acc[fs][t] = __builtin_amdgcn_mfma_f32_16x16x32_bf16(a[t], whi, acc[fs][t], 0, 0, 0);
                    acc[fs][t] = __builtin_amdgcn_mfma_f32_16x16x32_bf16(a[t], wmd, acc[fs][t], 0, 0, 0);
                    acc[fs][t] = __builtin_amdgcn_mfma_f32_16x16x32_bf16(a[t], wlo, acc[fs][t], 0, 0, 0);
                }
            }
        }
    }
    if (MODE == 1) {
        // spikes: identical order/values as before; collect (fs,reg,t) flags into one u64
        u64 allbits = 0ull;
        #pragma unroll
        for (int fs = 0; fs < 4; ++fs) {
            int f = f0 + fs*16 + l15;
            #pragma unroll
            for (int reg = 0; reg < 4; ++reg) {
                int n = n_base + lg*4 + reg;
                float v = 0.f;
                #pragma unroll
                for (int t = 0; t < TT; ++t) {
                    int ch = t*F + f;
                    float y = (acc[fs][t][reg] - st[(size_t)ch*2+0])*st[(size_t)ch*2+1]*ga[ch] + be[ch];
                    float s = lif_step(v, y);
                    if (s != 0.f) allbits |= 1ull << ((fs*4+reg)*4 + t);
                    outp[((size_t)(t*BB+b)*NPTS + n)*F + f] = (s != 0.f) ? (u16)0x3F80 : (u16)0;
                }
            }
        }
        // fused repack: per t, stage spike bytes [n_local][f_local], ballot per channel
        #pragma unroll
        for (int t = 0; t < TT; ++t) {
            __syncthreads();
            #pragma unroll
            for (int fs = 0; fs < 4; ++fs)
                #pragma unroll
                for (int reg = 0; reg < 4; ++reg)
                    btile[(wave*16 + lg*4 + reg)*68 + fs*16 + l15] =
                        (u8)((allbits >> ((fs*4+reg)*4 + t)) & 1ull);
            __syncthreads();
            #pragma unroll
            for (int cc = 0; cc < 16; ++cc) {
                u64 m = __ballot(btile[lane*68 + wave*16 + cc] != 0);
                if (lane == 0)
                    outb[((size_t)(t*BB+b)*F + f0 + wave*16 + cc)*32 + blockIdx.x] = m;
            }
        }
    } else if (MODE == 3) {
        #pragma unroll
        for (int fs = 0; fs < 4; ++fs) {
            int f = f0 + fs*16 + l15;
            u32 nib = 0u;
            #pragma unroll
            for (int reg = 0; reg < 4; ++reg) {
                float v = 0.f;
                #pragma unroll
                for (int t = 0; t < TT; ++t) {
                    int ch = t*F + f;
                    float y = (acc[fs][t][reg] - st[(size_t)ch*2+0])*st[(size_t)ch*2+1]*ga[ch] + be[ch];
                    float s = lif_step(v, y);
                    if (s != 0.f) nib |= (1u << t);
                }
            }
            nib |= __shfl_xor(nib, 16, 64);
            nib |= __shfl_xor(nib, 32, 64);
            if (lg == 0) {
                int n_pt = n_base >> 4;
                #pragma unroll
                for (int t = 0; t < TT; ++t)
                    outp[((size_t)(t*BB+b)*(NPTS>>4) + n_pt)*F + f] = ((nib>>t)&1u) ? (u16)0x3F80 : (u16)0;
            }
        }
    } else {
        #pragma unroll
        for (int fs = 0; fs < 4; ++fs) {
            int f = f0 + fs*16 + l15;
            u32 any[TT] = {0,0,0,0};
            float bb = (MODE == 0) ? bias[f] : 0.f;
            #pragma unroll
            for (int reg = 0; reg < 4; ++reg) {
                float v = 0.f;
                #pragma unroll
                for (int t = 0; t < TT; ++t) {
                    float y;
                    if (MODE == 0) y = acc[fs][t][reg] + bb;
                    else {
                        int ch = t*F + f;
                        y = (acc[fs][t][reg] - st[(size_t)ch*2+0])*st[(size_t)ch*2+1]*ga[ch] + be[ch];
                    }
                    float s = lif_step(v, y);
                    if (s != 0.f) any[t] = 1u;
                }
            }
            #pragma unroll
            for (int t = 0; t < TT; ++t) if (any[t]) atomicOr(&morr[t][fs*16+l15], 1u);
        }
        __syncthreads();
        for (int l = tid; l < TT*64; l += 256)
            if (morr[l>>6][l&63]) atomicOr(&outm[((size_t)((l>>6)*BB+b))*F + f0 + (l&63)], 1u);
    }
}

// repack point-major bf16-u16 spikes [t][b][n][C] -> channel-major bits [t][b][C][32 words over n]
template<int C>
__global__ __launch_bounds__(256) void k_repack(const u16* __restrict__ sp, u64* __restrict__ bits) {
    __shared__ u16 tile[64][C+2];
    int tid = threadIdx.x;
    int nw = blockIdx.x, b = blockIdx.y, t = blockIdx.z;
    const u16* src = sp + ((size_t)(t*BB+b)*NN + nw*64)*C;
    for (int i = tid*2; i < 64*C; i += 512) {
        u32 v = *(const u32*)(src + i);
        int r = i / C, c = i % C;
        *(u32*)&tile[r][c] = v;
    }
    __syncthreads();
    int wave = tid >> 6, lane = tid & 63;
    for (int c = wave; c < C; c += 4) {
        u64 m = __ballot(tile[lane][c] != 0);
        if (lane == 0) bits[((size_t)(t*BB+b)*C + c)*32 + nw] = m;
    }
}

__global__ __launch_bounds__(256) void k_out(const u32* __restrict__ mx4, float* __restrict__ out) {
    int i = blockIdx.x*256 + threadIdx.x;
    int b = i >> 10, g = i & 1023;
    float s = (float)(mx4[((size_t)0*BB+b)*1024+g] + mx4[((size_t)1*BB+b)*1024+g]
                    + mx4[((size_t)2*BB+b)*1024+g] + mx4[((size_t)3*BB+b)*1024+g]);
    out[i] = s * 0.25f;
}

extern "C" void kernel_launch(void* const* d_in, const int* in_sizes, int n_in,
                              void* d_out, int out_size, void* d_ws, size_t ws_size,
                              hipStream_t stream) {
    (void)in_sizes; (void)n_in; (void)out_size;
    const float* x    = (const float*)d_in[0];
    const float* tw1  = (const float*)d_in[1];
    const float* tb1  = (const float*)d_in[2];
    const float* tw2  = (const float*)d_in[3];
    const float* tb2  = (const float*)d_in[4];
    const float* tw3  = (const float*)d_in[5];
    const float* tb3  = (const float*)d_in[6];
    const float* tfw1 = (const float*)d_in[7];
    const float* tfb1 = (const float*)d_in[8];
    const float* tfw2 = (const float*)d_in[9];
    const float* tfb2 = (const float*)d_in[10];
    const float* tfw3 = (const float*)d_in[11];
    const float* tfb3 = (const float*)d_in[12];
    const float* w1   = (const float*)d_in[13];
    const float* w2   = (const float*)d_in[14];
    const float* w3   = (const float*)d_in[15];
    const float* w4   = (const float*)d_in[16];
    const float* g1   = (const float*)d_in[17];
    const float* be1  = (const float*)d_in[18];
    const float* g2   = (const float*)d_in[19];
    const float* be2  = (const float*)d_in[20];
    const float* g3   = (const float*)d_in[21];
    const float* be3  = (const float*)d_in[22];
    const float* g4   = (const float*)d_in[23];
    const float* be4  = (const float*)d_in[24];

    char* wsb = (char*)d_ws;
    size_t off = 0;
    auto alloc = [&](size_t bytes) -> void* {
        void* p = wsb + off;
        off = (off + bytes + 255) & ~(size_t)255;
        return p;
    };
    u64* s1b   = (u64*)alloc(sizeof(u64)*(size_t)TT*BB*NN);
    u64* s2b   = (u64*)alloc(sizeof(u64)*(size_t)TT*BB*NN*2);
    // mx and mx4 contiguous -> single memset covers both
    u32* mx    = (u32*)alloc(sizeof(u32)*(size_t)TT*BB*1024);
    u32* mx4   = (u32*)alloc(sizeof(u32)*(size_t)TT*BB*1024);
    float* trs = (float*)alloc(sizeof(float)*BB*9);
    float* xa  = (float*)alloc(sizeof(float)*(size_t)BB*14*NN);
    float4* xa4 = (float4*)alloc(sizeof(float4)*(size_t)BB*NN);
    int* idx   = (int*)alloc(sizeof(int)*(size_t)BB*NN*KNB);
    float* z1  = (float*)alloc(sizeof(float)*(size_t)BB*64*PP);
    float* part1 = (float*)alloc(sizeof(float)*(size_t)1024*64*2);
    float* st1 = (float*)alloc(sizeof(float)*64*2);
    float* st2 = (float*)alloc(sizeof(float)*512*2);
    float* st3 = (float*)alloc(sizeof(float)*1024*2);
    float* st4 = (float*)alloc(sizeof(float)*4096*2);
    float* h1v = (float*)alloc(sizeof(float)*(size_t)TT*BB*512);
    float* h2v = (float*)alloc(sizeof(float)*(size_t)TT*BB*256);
    u64* h1b = (u64*)alloc(sizeof(u64)*(size_t)TT*BB*64*512);
    u64* h1n = (u64*)alloc(sizeof(u64)*(size_t)TT*BB*PP);
    u16* m2p = (u16*)alloc(sizeof(u16)*(size_t)TT*BB*NN*128);
    u16* h3p = (u16*)alloc(sizeof(u16)*(size_t)TT*BB*NN*256);
    u64* m2b = (u64*)alloc(sizeof(u64)*(size_t)TT*BB*128*32);
    u64* h3b = (u64*)alloc(sizeof(u64)*(size_t)TT*BB*256*32);
    // Gram buffers contiguous -> single memset covers all three
    int* Mi64  = (int*)alloc(sizeof(int)*(size_t)TT*64*64);
    int* Mi128 = (int*)alloc(sizeof(int)*(size_t)TT*128*128);
    int* Mi256 = (int*)alloc(sizeof(int)*(size_t)TT*256*256);
    short* wp2h = (short*)alloc(sizeof(short)*(size_t)128*64);
    short* wp2m = (short*)alloc(sizeof(short)*(size_t)128*64);
    short* wp2l = (short*)alloc(sizeof(short)*(size_t)128*64);
    short* wp3h = (short*)alloc(sizeof(short)*(size_t)256*128);
    short* wp3m = (short*)alloc(sizeof(short)*(size_t)256*128);
    short* wp3l = (short*)alloc(sizeof(short)*(size_t)256*128);
    short* wp4h = (short*)alloc(sizeof(short)*(size_t)1024*256);
    short* wp4m = (short*)alloc(sizeof(short)*(size_t)1024*256);
    short* wp4l = (short*)alloc(sizeof(short)*(size_t)1024*256);
    short* wpth = (short*)alloc(sizeof(short)*(size_t)1024*128);
    short* wptm = (short*)alloc(sizeof(short)*(size_t)1024*128);
    short* wptl = (short*)alloc(sizeof(short)*(size_t)1024*128);
    if (off > ws_size) return;

    // merged memsets (contiguous, 256B-size-aligned regions)
    hipMemsetAsync(mx, 0, sizeof(u32)*(size_t)TT*BB*1024*2, stream);
    hipMemsetAsync(Mi64, 0, sizeof(int)*((size_t)TT*64*64 + (size_t)TT*128*128 + (size_t)TT*256*256), stream);

    // merged weight prep (exact 3-way bf16 split, all four tensors)
    k_wprep_all<<<dim3(1696), dim3(256), 0, stream>>>(w2, w3, w4, tw3,
        wp2h, wp2m, wp2l, wp3h, wp3m, wp3l, wp4h, wp4m, wp4l, wpth, wptm, wptl);

    // T-Net
    k_tnet1<<<dim3(64), dim3(256), 0, stream>>>(x, tw1, tb1, s1b);
    k_tnet2<<<dim3(64, 4), dim3(256), 0, stream>>>(s1b, tw2, tb2, (u32*)s2b);
    k_mconv<128,1024,0,true><<<dim3(32,16,8), dim3(256), 0, stream>>>(
        s2b, wpth, wptm, wptl, nullptr, nullptr, nullptr, tb3, nullptr, mx, nullptr, NN);
    k_fc1<<<dim3(512, 8), dim3(64), 0, stream>>>(mx, tfw1, tfb1, h1v);
    k_fc2<<<dim3(256, 8), dim3(64), 0, stream>>>(h1v, tfw2, tfb2, h2v);
    k_fc3<<<dim3(8), dim3(64), 0, stream>>>(h2v, tfw3, tfb3, trs);
    k_trans<<<dim3(64), dim3(256), 0, stream>>>(x, trs, xa, xa4);
    // KNN (wave-per-query)
    k_knn<<<dim3(NN/4, BB), dim3(256), 0, stream>>>(xa4, idx);
    // fused graph-feature + edge conv1 GEMM (z once) + stats partials
    k_zstats<<<dim3(128, 8), dim3(256), 0, stream>>>(xa, idx, w1, part1, z1);
    k_reduce<<<dim3(64), dim3(256), 0, stream>>>(part1, st1, 64, 1024, 262144.0);
    k_h1<<<dim3(128, 8), dim3(256), 0, stream>>>(z1, st1, g1, be1, h1b, h1n);
    // edge conv2: stats via tiled Gram, apply via MFMA (+ max over k)
    k_gram_h1<<<dim3(8, TT*BB), dim3(256), 0, stream>>>(h1b, Mi64);
    k_proj<64><<<dim3(128, TT), dim3(64), 0, stream>>>(Mi64, w2, st2, 128, 262144.0);
    k_mconv<64,128,3,true><<<dim3(PP/64,2,8), dim3(256), 0, stream>>>(
        h1n, wp2h, wp2m, wp2l, st2, g2, be2, nullptr, m2p, nullptr, nullptr, PP);
    k_repack<128><<<dim3(32,8,4), dim3(256), 0, stream>>>(m2p, m2b);
    // conv3 (MODE 1 emits h3p AND h3b; repack<256> fused away)
    k_gram2<128><<<dim3(2,2,TT*BB), dim3(256), 0, stream>>>(m2b, Mi128);
    k_proj<128><<<dim3(256, TT), dim3(128), 0, stream>>>(Mi128, w3, st3, 256, 16384.0);
    k_mconv<128,256,1,false><<<dim3(32,4,8), dim3(256), 0, stream>>>(
        m2p, wp3h, wp3m, wp3l, st3, g3, be3, nullptr, h3p, nullptr, h3b, NN);
    // conv4
    k_gram2<256><<<dim3(4,4,TT*BB), dim3(256), 0, stream>>>(h3b, Mi256);
    k_proj<256><<<dim3(1024, TT), dim3(256), 0, stream>>>(Mi256, w4, st4, 1024, 16384.0);
    k_mconv<256,1024,2,false><<<dim3(32,16,8), dim3(256), 0, stream>>>(
        h3p, wp4h, wp4m, wp4l, st4, g4, be4, nullptr, nullptr, mx4, nullptr, NN);
    // output
    k_out<<<dim3(32), dim3(256), 0, stream>>>(mx4, (float*)d_out);
}